// Round 6
// baseline (20258.723 us; speedup 1.0000x reference)
//
#include <hip/hip_runtime.h>
#include <cstdint>
#include <cstring>
#include <vector>
#include <algorithm>

// ---------------------------------------------------------------------------
// GRASPLayer round 6: GRU with LDS-staged, swizzled W (coalesced L2 streaming,
// double-buffered chunks). Row-partitioned, zero inter-block communication,
// per-thread FMA order identical to round-5 PASS -> hfin bit-identical.
// kmeans/gcn/finalk verbatim from the passing round.
// ---------------------------------------------------------------------------

namespace {
constexpr int Nn = 2048;
constexpr int Tt = 128;
constexpr int Dd = 256;
constexpr int Hh = 256;
constexpr int Kk = 12;
constexpr int MAXIT = 100;
}

struct IdxArgs { int v[Kk]; };

__device__ __forceinline__ float sigm(float x) { return 1.0f / (1.0f + expf(-x)); }

// ---------------------------------------------------------------------------
// 256 blocks x 256 threads, 8 rows/block, thread c owns output column c.
// W consumed per step in 32 chunks [3][256 cols][16 k] (16 Wih + 16 Whh),
// double-buffered in LDS. XOR slot-swizzle makes both the coalesced stores
// and the (k-uniform, col-varying) b128 reads bank-conflict-free.
__global__ __launch_bounds__(256, 1) void gru_staged(
    const float* __restrict__ x, const int* __restrict__ len,
    const float* __restrict__ Wih, const float* __restrict__ Whh,
    const float* __restrict__ bih, const float* __restrict__ bhh,
    float* __restrict__ hfin)
{
  __shared__ alignas(16) float wbuf[2][3][256][16];   // 98.3 KB
  __shared__ alignas(16) float xls[8][260];           // 8.3 KB
  __shared__ alignas(16) float hls[8][260];           // 8.3 KB
  const int tid = threadIdx.x;
  const int n0 = blockIdx.x * 8;
  const int C = tid;
  const int myswz = (C >> 1) & 3;

  const float bi_r = bih[C],          bh_r = bhh[C];
  const float bi_z = bih[Hh + C],     bh_z = bhh[Hh + C];
  const float bi_n = bih[2 * Hh + C], bh_n = bhh[2 * Hh + C];
  int L[8];
  #pragma unroll
  for (int r = 0; r < 8; ++r) L[r] = len[n0 + r];

  // Staging geometry: thread handles W-rows frow = (tid>>2) + 64*i (i<12) of
  // the flattened [768 x 256] matrix, 16B at within-row offset (tid&3)*16B.
  // -> 4 lanes cover one 64B line fully; 16 rows per wave. Coalesced in L2.
  const int wrow0 = tid >> 2;
  const int kof = (tid & 3) * 4;
  const float* __restrict__ ihbase = Wih + (size_t)wrow0 * 256 + kof;
  const float* __restrict__ hhbase = Whh + (size_t)wrow0 * 256 + kof;
  int ldsoff[12];
  #pragma unroll
  for (int i = 0; i < 12; ++i) {
    int frow = wrow0 + 64 * i;                       // = g*256 + c
    int slot = (tid & 3) ^ ((frow >> 1) & 3);        // XOR swizzle
    ldsoff[i] = frow * 16 + slot * 4;                // floats
  }

  // ---- prologue: h = 0, stage x_0, stage chunk 0 (Wih k=0..15) into buf 0
  #pragma unroll
  for (int r = 0; r < 8; ++r) hls[r][tid] = 0.f;
  #pragma unroll
  for (int i2 = 0; i2 < 2; ++i2) {
    int f = tid + i2 * 256; int row = f >> 6, c4 = f & 63;
    *(float4*)&xls[row][c4 * 4] =
        *(const float4*)&x[(size_t)(n0 + row) * (Tt * Dd) + c4 * 4];
  }
  {
    float4 tmp[12];
    #pragma unroll
    for (int i = 0; i < 12; ++i)
      tmp[i] = *(const float4*)(ihbase + (size_t)i * 64 * 256);
    float* wb = &wbuf[0][0][0][0];
    #pragma unroll
    for (int i = 0; i < 12; ++i) *(float4*)(wb + ldsoff[i]) = tmp[i];
  }
  __syncthreads();

  int buf = 0;
  #pragma unroll 1
  for (int t = 0; t < Tt; ++t) {
    float aR[8] = {}, aZ[8] = {}, aXN[8] = {}, aHN[8] = {};
    #pragma unroll 1
    for (int cc = 0; cc < 32; ++cc) {
      // ---- issue next-chunk loads (before compute: latency hides under FMAs)
      float4 tmp[12];
      const bool do_st = !(t == Tt - 1 && cc == 31);
      const int nc = (cc == 31) ? 0 : cc + 1;
      if (do_st) {
        const float* src = (nc < 16) ? ihbase : hhbase;
        const int k0 = (nc & 15) * 16;
        #pragma unroll
        for (int i = 0; i < 12; ++i)
          tmp[i] = *(const float4*)(src + (size_t)i * 64 * 256 + k0);
      }

      // ---- compute current chunk (16 k), FMA order identical to round 5
      const int kk = (cc & 15) * 16;
      if (cc < 16) {
        #pragma unroll
        for (int j4 = 0; j4 < 4; ++j4) {
          const int k = kk + j4 * 4;
          const int sl = (j4 ^ myswz) * 4;
          float4 wr = *(const float4*)&wbuf[buf][0][C][sl];
          float4 wz = *(const float4*)&wbuf[buf][1][C][sl];
          float4 wn = *(const float4*)&wbuf[buf][2][C][sl];
          #pragma unroll
          for (int r = 0; r < 8; ++r) {
            float4 xv = *(const float4*)&xls[r][k];
            aR[r]  += xv.x * wr.x; aR[r]  += xv.y * wr.y;
            aR[r]  += xv.z * wr.z; aR[r]  += xv.w * wr.w;
            aZ[r]  += xv.x * wz.x; aZ[r]  += xv.y * wz.y;
            aZ[r]  += xv.z * wz.z; aZ[r]  += xv.w * wz.w;
            aXN[r] += xv.x * wn.x; aXN[r] += xv.y * wn.y;
            aXN[r] += xv.z * wn.z; aXN[r] += xv.w * wn.w;
          }
        }
      } else {
        #pragma unroll
        for (int j4 = 0; j4 < 4; ++j4) {
          const int k = kk + j4 * 4;
          const int sl = (j4 ^ myswz) * 4;
          float4 wr = *(const float4*)&wbuf[buf][0][C][sl];
          float4 wz = *(const float4*)&wbuf[buf][1][C][sl];
          float4 wn = *(const float4*)&wbuf[buf][2][C][sl];
          #pragma unroll
          for (int r = 0; r < 8; ++r) {
            float4 hv = *(const float4*)&hls[r][k];
            aR[r]  += hv.x * wr.x; aR[r]  += hv.y * wr.y;
            aR[r]  += hv.z * wr.z; aR[r]  += hv.w * wr.w;
            aZ[r]  += hv.x * wz.x; aZ[r]  += hv.y * wz.y;
            aZ[r]  += hv.z * wz.z; aZ[r]  += hv.w * wz.w;
            aHN[r] += hv.x * wn.x; aHN[r] += hv.y * wn.y;
            aHN[r] += hv.z * wn.z; aHN[r] += hv.w * wn.w;
          }
        }
      }

      // stage x_{t+1} once per step (xls reads for step t ended at cc==15)
      if (cc == 16 && t + 1 < Tt) {
        #pragma unroll
        for (int i2 = 0; i2 < 2; ++i2) {
          int f = tid + i2 * 256; int row = f >> 6, c4 = f & 63;
          *(float4*)&xls[row][c4 * 4] =
              *(const float4*)&x[(size_t)(n0 + row) * (Tt * Dd)
                                 + (size_t)(t + 1) * Dd + c4 * 4];
        }
      }

      // ---- write staged chunk into the other buffer
      if (do_st) {
        float* wb = &wbuf[buf ^ 1][0][0][0];
        #pragma unroll
        for (int i = 0; i < 12; ++i) *(float4*)(wb + ldsoff[i]) = tmp[i];
      }
      __syncthreads();

      if (cc == 31) {
        // all phase-B readers of hls are past the barrier: safe to update
        #pragma unroll
        for (int r = 0; r < 8; ++r) {
          if (t < L[r]) {
            float rg = sigm(aR[r] + bi_r + bh_r);
            float zg = sigm(aZ[r] + bi_z + bh_z);
            float ng = tanhf(aXN[r] + bi_n + rg * (aHN[r] + bh_n));
            float hv = (1.f - zg) * ng + zg * hls[r][C];
            hls[r][C] = hv;
            if (t == L[r] - 1) hfin[(size_t)(n0 + r) * Hh + C] = hv;
          }
        }
        __syncthreads();
      }
      buf ^= 1;
    }
  }
}

// ---------------------------------------------------------------------------
__global__ void km_init(const float* __restrict__ dat, float* __restrict__ cent, IdxArgs ia)
{
  int c = threadIdx.x;
  #pragma unroll
  for (int k = 0; k < Kk; ++k)
    cent[k * Hh + c] = dat[(size_t)ia.v[k] * Hh + c];
}

// Assign + per-block partial sums. Deterministic: per-wave LDS partials in
// fixed row order, combined in fixed wave order. No atomics. (verbatim)
__global__ __launch_bounds__(256) void km_assign(
    const float* __restrict__ dat, const float* __restrict__ cent,
    float* __restrict__ part, int* __restrict__ pcnt)
{
  __shared__ alignas(16) float cs[Kk][Hh];        // centers
  __shared__ alignas(16) float ps[4][Kk][Hh];     // per-wave partial sums
  __shared__ float c2s[Kk];
  __shared__ int pc[4][Kk];
  const int tid = threadIdx.x;
  const int lane = tid & 63;
  const int w = tid >> 6;

  for (int i = tid; i < Kk * Hh; i += 256) ((float*)cs)[i] = cent[i];
  for (int i = tid; i < 4 * Kk * Hh; i += 256) ((float*)ps)[i] = 0.f;
  if (tid < 4 * Kk) ((int*)pc)[tid] = 0;
  __syncthreads();
  if (tid < Kk) {
    float s = 0.f;
    for (int c = 0; c < Hh; ++c) { float v = cs[tid][c]; s += v * v; }
    c2s[tid] = s;
  }
  __syncthreads();

  const int base = blockIdx.x * 64 + w * 16;      // 16 rows per wave
  for (int rr = 0; rr < 16; ++rr) {
    const int n = base + rr;
    float4 v = *(const float4*)&dat[(size_t)n * Hh + lane * 4];
    float best = 3.4e38f; int bi = 0;
    #pragma unroll
    for (int k = 0; k < Kk; ++k) {
      float4 cv = *(const float4*)&cs[k][lane * 4];
      float p = v.x * cv.x + v.y * cv.y + v.z * cv.z + v.w * cv.w;
      #pragma unroll
      for (int m = 1; m < 64; m <<= 1) p += __shfl_xor(p, m, 64);
      float d = c2s[k] - 2.f * p;                 // x^2 constant per row
      if (d < best) { best = d; bi = k; }         // strict <: first-min = argmin
    }
    float4* dst = (float4*)&ps[w][bi][lane * 4];
    float4 cur = *dst;
    cur.x += v.x; cur.y += v.y; cur.z += v.z; cur.w += v.w;
    *dst = cur;
    if (lane == 0) pc[w][bi] += 1;
  }
  __syncthreads();
  const float* p0 = &ps[0][0][0];
  for (int i = tid; i < Kk * Hh; i += 256)
    part[(size_t)blockIdx.x * (Kk * Hh) + i] =
        p0[i] + p0[Kk * Hh + i] + p0[2 * Kk * Hh + i] + p0[3 * Kk * Hh + i];
  if (tid < Kk)
    pcnt[blockIdx.x * Kk + tid] = pc[0][tid] + pc[1][tid] + pc[2][tid] + pc[3][tid];
}

// Reduce 32 block-partials in fixed order; empty clusters keep old center.
__global__ __launch_bounds__(256) void km_update(
    const float* __restrict__ part, const int* __restrict__ pcnt,
    float* __restrict__ cent)
{
  int k = blockIdx.x, c = threadIdx.x;
  int cnt = 0;
  for (int p = 0; p < 32; ++p) cnt += pcnt[p * Kk + k];
  float s = 0.f;
  for (int p = 0; p < 32; ++p) s += part[(size_t)p * (Kk * Hh) + k * Hh + c];
  if (cnt > 0) cent[k * Hh + c] = s / (float)cnt;
}

// ---------------------------------------------------------------------------
// h1 = relu(centers@g1_w + g1_b); h2 = relu(h1@g2_w + g2_b). One block.
__global__ __launch_bounds__(256) void gcn(
    const float* __restrict__ cent, const float* __restrict__ g1w,
    const float* __restrict__ g1b, const float* __restrict__ g2w,
    const float* __restrict__ g2b, float* __restrict__ h2out)
{
  __shared__ float a[Kk][Hh];
  __shared__ float b[Kk][Hh];
  int c = threadIdx.x;
  for (int i = c; i < Kk * Hh; i += 256) ((float*)a)[i] = cent[i];
  __syncthreads();
  float acc[Kk];
  #pragma unroll
  for (int k = 0; k < Kk; ++k) acc[k] = 0.f;
  for (int j = 0; j < Hh; ++j) {
    float wv = g1w[(size_t)j * Hh + c];
    #pragma unroll
    for (int k = 0; k < Kk; ++k) acc[k] += a[k][j] * wv;
  }
  #pragma unroll
  for (int k = 0; k < Kk; ++k) b[k][c] = fmaxf(acc[k] + g1b[c], 0.f);
  __syncthreads();
  #pragma unroll
  for (int k = 0; k < Kk; ++k) acc[k] = 0.f;
  for (int j = 0; j < Hh; ++j) {
    float wv = g2w[(size_t)j * Hh + c];
    #pragma unroll
    for (int k = 0; k < Kk; ++k) acc[k] += b[k][j] * wv;
  }
  #pragma unroll
  for (int k = 0; k < Kk; ++k) h2out[k * Hh + c] = fmaxf(acc[k] + g2b[c], 0.f);
}

// scores = softmax(relu(ht@centers^T)); clu = scores@h2; gated blend. 1 block/row.
__global__ __launch_bounds__(256) void finalk(
    const float* __restrict__ hfin, const float* __restrict__ cent,
    const float* __restrict__ h2, const float* __restrict__ w1w,
    const float* __restrict__ w1b, const float* __restrict__ w2w,
    const float* __restrict__ w2b, float* __restrict__ out)
{
  __shared__ alignas(16) float cs[Kk][Hh];
  __shared__ alignas(16) float hs[Kk][Hh];
  __shared__ float red[4];
  const int tid = threadIdx.x, lane = tid & 63, w = tid >> 6;
  const int n = blockIdx.x;
  for (int i = tid; i < Kk * Hh; i += 256) { ((float*)cs)[i] = cent[i]; ((float*)hs)[i] = h2[i]; }
  float ht = hfin[(size_t)n * Hh + tid];
  __syncthreads();

  auto bred = [&](float v) -> float {
    #pragma unroll
    for (int m = 1; m < 64; m <<= 1) v += __shfl_xor(v, m, 64);
    __syncthreads();
    if (lane == 0) red[w] = v;
    __syncthreads();
    return red[0] + red[1] + red[2] + red[3];
  };

  float ev[Kk];
  #pragma unroll
  for (int k = 0; k < Kk; ++k)
    ev[k] = fmaxf(bred(ht * cs[k][tid]), 0.f);

  float mx = ev[0];
  #pragma unroll
  for (int k = 1; k < Kk; ++k) mx = fmaxf(mx, ev[k]);
  float se = 0.f; float sc[Kk];
  #pragma unroll
  for (int k = 0; k < Kk; ++k) { sc[k] = expf(ev[k] - mx); se += sc[k]; }
  float inv = 1.f / se;
  float clu = 0.f;
  #pragma unroll
  for (int k = 0; k < Kk; ++k) clu += sc[k] * inv * hs[k][tid];

  float r1 = bred(clu * w1w[tid]);
  float r2 = bred(ht * w2w[tid]);
  float a1 = sigm(r1 + w1b[0]);
  float a2 = sigm(r2 + w2b[0]);
  float wn = a1 / (a1 + a2);
  out[(size_t)n * Hh + tid] = wn * clu + (1.f - wn) * ht;
}

// ---------------------------------------------------------------------------
// Host-side threefry2x32 (JAX), reproducing jax.random.permutation(key(42), 2048)[:12].
static void tf2x32(uint32_t k0, uint32_t k1, uint32_t c0, uint32_t c1,
                   uint32_t& o0, uint32_t& o1) {
  uint32_t ks2 = k0 ^ k1 ^ 0x1BD11BDAu;
  uint32_t x0 = c0 + k0, x1 = c1 + k1;
#define TFR(r) do { x0 += x1; x1 = (x1 << (r)) | (x1 >> (32 - (r))); x1 ^= x0; } while (0)
  TFR(13); TFR(15); TFR(26); TFR(6);
  x0 += k1;  x1 += ks2 + 1u;
  TFR(17); TFR(29); TFR(16); TFR(24);
  x0 += ks2; x1 += k0 + 2u;
  TFR(13); TFR(15); TFR(26); TFR(6);
  x0 += k0;  x1 += k1 + 3u;
  TFR(17); TFR(29); TFR(16); TFR(24);
  x0 += k1;  x1 += ks2 + 4u;
  TFR(13); TFR(15); TFR(26); TFR(6);
  x0 += ks2; x1 += k0 + 5u;
#undef TFR
  o0 = x0; o1 = x1;
}

static void compute_idx(int* out12) {
  uint32_t kh = 0u, kl = 42u;     // jax.random.key(42) -> (0, 42)
  std::vector<int> perm(Nn);
  for (int i = 0; i < Nn; ++i) perm[i] = i;
  std::vector<uint32_t> bits(Nn);
  std::vector<int> pos(Nn);
  for (int round = 0; round < 2; ++round) {     // 2 rounds for n=2048
    uint32_t nh, nl, sh, sl;
    tf2x32(kh, kl, 0u, 0u, nh, nl);             // split: counters (0,0),(0,1)
    tf2x32(kh, kl, 0u, 1u, sh, sl);
    kh = nh; kl = nl;
    // partitionable random_bits(32): bits[i] = o0 ^ o1 at counter (0, i)
    for (uint32_t i = 0; i < (uint32_t)Nn; ++i) {
      uint32_t o0, o1; tf2x32(sh, sl, 0u, i, o0, o1); bits[i] = o0 ^ o1;
    }
    for (int i = 0; i < Nn; ++i) pos[i] = i;
    std::stable_sort(pos.begin(), pos.end(),
                     [&](int a, int b) { return bits[a] < bits[b]; });
    std::vector<int> np(Nn);
    for (int i = 0; i < Nn; ++i) np[i] = perm[pos[i]];
    perm.swap(np);
  }
  for (int k = 0; k < Kk; ++k) out12[k] = perm[k];
}

// ---------------------------------------------------------------------------
extern "C" void kernel_launch(void* const* d_in, const int* in_sizes, int n_in,
                              void* d_out, int out_size, void* d_ws, size_t ws_size,
                              hipStream_t stream) {
  const float* x   = (const float*)d_in[0];
  const int*   len = (const int*)d_in[1];
  const float* Wih = (const float*)d_in[2];
  const float* Whh = (const float*)d_in[3];
  const float* bih = (const float*)d_in[4];
  const float* bhh = (const float*)d_in[5];
  const float* w1w = (const float*)d_in[6];
  const float* w1b = (const float*)d_in[7];
  const float* w2w = (const float*)d_in[8];
  const float* w2b = (const float*)d_in[9];
  const float* g1w = (const float*)d_in[10];
  const float* g1b = (const float*)d_in[11];
  const float* g2w = (const float*)d_in[12];
  const float* g2b = (const float*)d_in[13];
  float* out = (float*)d_out;

  float* wsf  = (float*)d_ws;
  float* hfin = wsf;                        // N*H
  float* cent = hfin + (size_t)Nn * Hh;     // K*H
  float* h2g  = cent + Kk * Hh;             // K*H
  float* part = h2g + Kk * Hh;              // 32*K*H
  int*   pcnt = (int*)(part + 32 * Kk * Hh);// 32*K

  IdxArgs ia;
  compute_idx(ia.v);                        // host, deterministic, capture-safe

  gru_staged<<<256, 256, 0, stream>>>(x, len, Wih, Whh, bih, bhh, hfin);

  km_init<<<1, 256, 0, stream>>>(hfin, cent, ia);
  for (int it = 0; it < MAXIT; ++it) {
    km_assign<<<32, 256, 0, stream>>>(hfin, cent, part, pcnt);
    km_update<<<Kk, 256, 0, stream>>>(part, pcnt, cent);
  }

  gcn<<<1, 256, 0, stream>>>(cent, g1w, g1b, g2w, g2b, h2g);
  finalk<<<Nn, 256, 0, stream>>>(hfin, cent, h2g, w1w, w1b, w2w, w2b, out);
}

// Round 7
// 8836.077 us; speedup vs baseline: 2.2927x; 2.2927x over previous
//
#include <hip/hip_runtime.h>
#include <cstdint>
#include <cstring>
#include <vector>
#include <algorithm>

// ---------------------------------------------------------------------------
// GRASPLayer round 7: GRU with pre-packed W (coalesced per-lane float4 loads,
// no LDS staging, registers only) + 512-thread blocks (8 waves/CU).
// Per-thread FMA order identical to rounds 3/5 PASS -> hfin bit-identical.
// kmeans/gcn/finalk verbatim from the passing rounds.
// ---------------------------------------------------------------------------

namespace {
constexpr int Nn = 2048;
constexpr int Tt = 128;
constexpr int Dd = 256;
constexpr int Hh = 256;
constexpr int Kk = 12;
constexpr int MAXIT = 100;
}

struct IdxArgs { int v[Kk]; };

__device__ __forceinline__ float sigm(float x) { return 1.0f / (1.0f + expf(-x)); }

// ---------------------------------------------------------------------------
// Pack Wih/Whh [3*256 x 256] row-major into pk[k4][w][c][4], w in {ihr,ihz,ihn,
// hhr,hhz,hhn}. In the GRU loop, lane c reads pk[k4][w][c][0..3]: consecutive
// lanes -> consecutive 16B -> fully coalesced, every byte used.
__global__ __launch_bounds__(64) void pack_w(
    const float* __restrict__ Wih, const float* __restrict__ Whh,
    float* __restrict__ pk)
{
  const int j = blockIdx.x;            // 0..767 = w-row (g*256 + c)
  const int k4 = threadIdx.x;          // 0..63
  const int g = j >> 8, c = j & 255;
  float4 vih = *(const float4*)&Wih[(size_t)j * 256 + k4 * 4];
  float4 vhh = *(const float4*)&Whh[(size_t)j * 256 + k4 * 4];
  *(float4*)&pk[(((size_t)k4 * 6 + g) * 256 + c) * 4]       = vih;
  *(float4*)&pk[(((size_t)k4 * 6 + 3 + g) * 256 + c) * 4]   = vhh;
}

// ---------------------------------------------------------------------------
// 256 blocks x 512 threads; block owns 8 rows; thread (c, half) computes
// column c of rows half*4..half*4+3. W streamed coalesced from pk (L1/L2).
// x/h staged in LDS, read as same-address b128 broadcasts (conflict-free).
__global__ __launch_bounds__(512, 1) void gru_packed(
    const float* __restrict__ x, const int* __restrict__ len,
    const float* __restrict__ pk,
    const float* __restrict__ bih, const float* __restrict__ bhh,
    float* __restrict__ hfin)
{
  __shared__ alignas(16) float xls[8][260];
  __shared__ alignas(16) float hls[8][260];
  const int tid = threadIdx.x;
  const int C = tid & 255;
  const int r0 = (tid >> 8) * 4;             // rows r0..r0+3
  const int n0 = blockIdx.x * 8;

  const float bi_r = bih[C],          bh_r = bhh[C];
  const float bi_z = bih[Hh + C],     bh_z = bhh[Hh + C];
  const float bi_n = bih[2 * Hh + C], bh_n = bhh[2 * Hh + C];
  int L[4];
  #pragma unroll
  for (int r = 0; r < 4; ++r) L[r] = len[n0 + r0 + r];

  const float* __restrict__ p0 = pk + (size_t)C * 4;   // + k4*6144 + w*1024

  #pragma unroll
  for (int r = 0; r < 4; ++r) hls[r0 + r][C] = 0.f;
  __syncthreads();

  for (int t = 0; t < Tt; ++t) {
    // stage x_t rows (512 f4, one per thread, coalesced)
    {
      int row = tid >> 6, c4 = tid & 63;
      *(float4*)&xls[row][c4 * 4] =
          *(const float4*)&x[(size_t)(n0 + row) * (Tt * Dd) + (size_t)t * Dd + c4 * 4];
    }
    __syncthreads();

    float aR[4] = {}, aZ[4] = {}, aXN[4] = {}, aHN[4] = {};

    // ---- phase A: gx = x_t @ W_ih^T, k ascending (order == round 5) ----
    for (int k4 = 0; k4 < 64; ++k4) {
      const float* pkk = p0 + (size_t)k4 * 6144;
      float4 wr = *(const float4*)(pkk);
      float4 wz = *(const float4*)(pkk + 1024);
      float4 wn = *(const float4*)(pkk + 2048);
      const int k = k4 * 4;
      #pragma unroll
      for (int r = 0; r < 4; ++r) {
        float4 xv = *(const float4*)&xls[r0 + r][k];   // broadcast read
        aR[r]  += xv.x * wr.x; aR[r]  += xv.y * wr.y;
        aR[r]  += xv.z * wr.z; aR[r]  += xv.w * wr.w;
        aZ[r]  += xv.x * wz.x; aZ[r]  += xv.y * wz.y;
        aZ[r]  += xv.z * wz.z; aZ[r]  += xv.w * wz.w;
        aXN[r] += xv.x * wn.x; aXN[r] += xv.y * wn.y;
        aXN[r] += xv.z * wn.z; aXN[r] += xv.w * wn.w;
      }
    }
    // ---- phase B: gh = h_{t-1} @ W_hh^T (continues aR/aZ; aHN separate) ----
    for (int k4 = 0; k4 < 64; ++k4) {
      const float* pkk = p0 + (size_t)k4 * 6144;
      float4 wr = *(const float4*)(pkk + 3072);
      float4 wz = *(const float4*)(pkk + 4096);
      float4 wn = *(const float4*)(pkk + 5120);
      const int k = k4 * 4;
      #pragma unroll
      for (int r = 0; r < 4; ++r) {
        float4 hv = *(const float4*)&hls[r0 + r][k];   // broadcast read
        aR[r]  += hv.x * wr.x; aR[r]  += hv.y * wr.y;
        aR[r]  += hv.z * wr.z; aR[r]  += hv.w * wr.w;
        aZ[r]  += hv.x * wz.x; aZ[r]  += hv.y * wz.y;
        aZ[r]  += hv.z * wz.z; aZ[r]  += hv.w * wz.w;
        aHN[r] += hv.x * wn.x; aHN[r] += hv.y * wn.y;
        aHN[r] += hv.z * wn.z; aHN[r] += hv.w * wn.w;
      }
    }
    __syncthreads();                        // phase-B readers of hls done

    // ---- gates (order r,z,n; PyTorch layout) + block-local h update ----
    #pragma unroll
    for (int r = 0; r < 4; ++r) {
      if (t < L[r]) {
        float rg = sigm(aR[r] + bi_r + bh_r);
        float zg = sigm(aZ[r] + bi_z + bh_z);
        float ng = tanhf(aXN[r] + bi_n + rg * (aHN[r] + bh_n));
        float hv = (1.f - zg) * ng + zg * hls[r0 + r][C];
        hls[r0 + r][C] = hv;
        if (t == L[r] - 1) hfin[(size_t)(n0 + r0 + r) * Hh + C] = hv;
      }
    }
    // next iteration's top __syncthreads orders these writes before reads
  }
}

// ---------------------------------------------------------------------------
__global__ void km_init(const float* __restrict__ dat, float* __restrict__ cent, IdxArgs ia)
{
  int c = threadIdx.x;
  #pragma unroll
  for (int k = 0; k < Kk; ++k)
    cent[k * Hh + c] = dat[(size_t)ia.v[k] * Hh + c];
}

// Assign + per-block partial sums. Deterministic: per-wave LDS partials in
// fixed row order, combined in fixed wave order. No atomics. (verbatim)
__global__ __launch_bounds__(256) void km_assign(
    const float* __restrict__ dat, const float* __restrict__ cent,
    float* __restrict__ part, int* __restrict__ pcnt)
{
  __shared__ alignas(16) float cs[Kk][Hh];        // centers
  __shared__ alignas(16) float ps[4][Kk][Hh];     // per-wave partial sums
  __shared__ float c2s[Kk];
  __shared__ int pc[4][Kk];
  const int tid = threadIdx.x;
  const int lane = tid & 63;
  const int w = tid >> 6;

  for (int i = tid; i < Kk * Hh; i += 256) ((float*)cs)[i] = cent[i];
  for (int i = tid; i < 4 * Kk * Hh; i += 256) ((float*)ps)[i] = 0.f;
  if (tid < 4 * Kk) ((int*)pc)[tid] = 0;
  __syncthreads();
  if (tid < Kk) {
    float s = 0.f;
    for (int c = 0; c < Hh; ++c) { float v = cs[tid][c]; s += v * v; }
    c2s[tid] = s;
  }
  __syncthreads();

  const int base = blockIdx.x * 64 + w * 16;      // 16 rows per wave
  for (int rr = 0; rr < 16; ++rr) {
    const int n = base + rr;
    float4 v = *(const float4*)&dat[(size_t)n * Hh + lane * 4];
    float best = 3.4e38f; int bi = 0;
    #pragma unroll
    for (int k = 0; k < Kk; ++k) {
      float4 cv = *(const float4*)&cs[k][lane * 4];
      float p = v.x * cv.x + v.y * cv.y + v.z * cv.z + v.w * cv.w;
      #pragma unroll
      for (int m = 1; m < 64; m <<= 1) p += __shfl_xor(p, m, 64);
      float d = c2s[k] - 2.f * p;                 // x^2 constant per row
      if (d < best) { best = d; bi = k; }         // strict <: first-min = argmin
    }
    float4* dst = (float4*)&ps[w][bi][lane * 4];
    float4 cur = *dst;
    cur.x += v.x; cur.y += v.y; cur.z += v.z; cur.w += v.w;
    *dst = cur;
    if (lane == 0) pc[w][bi] += 1;
  }
  __syncthreads();
  const float* p0 = &ps[0][0][0];
  for (int i = tid; i < Kk * Hh; i += 256)
    part[(size_t)blockIdx.x * (Kk * Hh) + i] =
        p0[i] + p0[Kk * Hh + i] + p0[2 * Kk * Hh + i] + p0[3 * Kk * Hh + i];
  if (tid < Kk)
    pcnt[blockIdx.x * Kk + tid] = pc[0][tid] + pc[1][tid] + pc[2][tid] + pc[3][tid];
}

// Reduce 32 block-partials in fixed order; empty clusters keep old center.
__global__ __launch_bounds__(256) void km_update(
    const float* __restrict__ part, const int* __restrict__ pcnt,
    float* __restrict__ cent)
{
  int k = blockIdx.x, c = threadIdx.x;
  int cnt = 0;
  for (int p = 0; p < 32; ++p) cnt += pcnt[p * Kk + k];
  float s = 0.f;
  for (int p = 0; p < 32; ++p) s += part[(size_t)p * (Kk * Hh) + k * Hh + c];
  if (cnt > 0) cent[k * Hh + c] = s / (float)cnt;
}

// ---------------------------------------------------------------------------
// h1 = relu(centers@g1_w + g1_b); h2 = relu(h1@g2_w + g2_b). One block.
__global__ __launch_bounds__(256) void gcn(
    const float* __restrict__ cent, const float* __restrict__ g1w,
    const float* __restrict__ g1b, const float* __restrict__ g2w,
    const float* __restrict__ g2b, float* __restrict__ h2out)
{
  __shared__ float a[Kk][Hh];
  __shared__ float b[Kk][Hh];
  int c = threadIdx.x;
  for (int i = c; i < Kk * Hh; i += 256) ((float*)a)[i] = cent[i];
  __syncthreads();
  float acc[Kk];
  #pragma unroll
  for (int k = 0; k < Kk; ++k) acc[k] = 0.f;
  for (int j = 0; j < Hh; ++j) {
    float wv = g1w[(size_t)j * Hh + c];
    #pragma unroll
    for (int k = 0; k < Kk; ++k) acc[k] += a[k][j] * wv;
  }
  #pragma unroll
  for (int k = 0; k < Kk; ++k) b[k][c] = fmaxf(acc[k] + g1b[c], 0.f);
  __syncthreads();
  #pragma unroll
  for (int k = 0; k < Kk; ++k) acc[k] = 0.f;
  for (int j = 0; j < Hh; ++j) {
    float wv = g2w[(size_t)j * Hh + c];
    #pragma unroll
    for (int k = 0; k < Kk; ++k) acc[k] += b[k][j] * wv;
  }
  #pragma unroll
  for (int k = 0; k < Kk; ++k) h2out[k * Hh + c] = fmaxf(acc[k] + g2b[c], 0.f);
}

// scores = softmax(relu(ht@centers^T)); clu = scores@h2; gated blend. 1 block/row.
__global__ __launch_bounds__(256) void finalk(
    const float* __restrict__ hfin, const float* __restrict__ cent,
    const float* __restrict__ h2, const float* __restrict__ w1w,
    const float* __restrict__ w1b, const float* __restrict__ w2w,
    const float* __restrict__ w2b, float* __restrict__ out)
{
  __shared__ alignas(16) float cs[Kk][Hh];
  __shared__ alignas(16) float hs[Kk][Hh];
  __shared__ float red[4];
  const int tid = threadIdx.x, lane = tid & 63, w = tid >> 6;
  const int n = blockIdx.x;
  for (int i = tid; i < Kk * Hh; i += 256) { ((float*)cs)[i] = cent[i]; ((float*)hs)[i] = h2[i]; }
  float ht = hfin[(size_t)n * Hh + tid];
  __syncthreads();

  auto bred = [&](float v) -> float {
    #pragma unroll
    for (int m = 1; m < 64; m <<= 1) v += __shfl_xor(v, m, 64);
    __syncthreads();
    if (lane == 0) red[w] = v;
    __syncthreads();
    return red[0] + red[1] + red[2] + red[3];
  };

  float ev[Kk];
  #pragma unroll
  for (int k = 0; k < Kk; ++k)
    ev[k] = fmaxf(bred(ht * cs[k][tid]), 0.f);

  float mx = ev[0];
  #pragma unroll
  for (int k = 1; k < Kk; ++k) mx = fmaxf(mx, ev[k]);
  float se = 0.f; float sc[Kk];
  #pragma unroll
  for (int k = 0; k < Kk; ++k) { sc[k] = expf(ev[k] - mx); se += sc[k]; }
  float inv = 1.f / se;
  float clu = 0.f;
  #pragma unroll
  for (int k = 0; k < Kk; ++k) clu += sc[k] * inv * hs[k][tid];

  float r1 = bred(clu * w1w[tid]);
  float r2 = bred(ht * w2w[tid]);
  float a1 = sigm(r1 + w1b[0]);
  float a2 = sigm(r2 + w2b[0]);
  float wn = a1 / (a1 + a2);
  out[(size_t)n * Hh + tid] = wn * clu + (1.f - wn) * ht;
}

// ---------------------------------------------------------------------------
// Host-side threefry2x32 (JAX), reproducing jax.random.permutation(key(42), 2048)[:12].
static void tf2x32(uint32_t k0, uint32_t k1, uint32_t c0, uint32_t c1,
                   uint32_t& o0, uint32_t& o1) {
  uint32_t ks2 = k0 ^ k1 ^ 0x1BD11BDAu;
  uint32_t x0 = c0 + k0, x1 = c1 + k1;
#define TFR(r) do { x0 += x1; x1 = (x1 << (r)) | (x1 >> (32 - (r))); x1 ^= x0; } while (0)
  TFR(13); TFR(15); TFR(26); TFR(6);
  x0 += k1;  x1 += ks2 + 1u;
  TFR(17); TFR(29); TFR(16); TFR(24);
  x0 += ks2; x1 += k0 + 2u;
  TFR(13); TFR(15); TFR(26); TFR(6);
  x0 += k0;  x1 += k1 + 3u;
  TFR(17); TFR(29); TFR(16); TFR(24);
  x0 += k1;  x1 += ks2 + 4u;
  TFR(13); TFR(15); TFR(26); TFR(6);
  x0 += ks2; x1 += k0 + 5u;
#undef TFR
  o0 = x0; o1 = x1;
}

static void compute_idx(int* out12) {
  uint32_t kh = 0u, kl = 42u;     // jax.random.key(42) -> (0, 42)
  std::vector<int> perm(Nn);
  for (int i = 0; i < Nn; ++i) perm[i] = i;
  std::vector<uint32_t> bits(Nn);
  std::vector<int> pos(Nn);
  for (int round = 0; round < 2; ++round) {     // 2 rounds for n=2048
    uint32_t nh, nl, sh, sl;
    tf2x32(kh, kl, 0u, 0u, nh, nl);             // split: counters (0,0),(0,1)
    tf2x32(kh, kl, 0u, 1u, sh, sl);
    kh = nh; kl = nl;
    // partitionable random_bits(32): bits[i] = o0 ^ o1 at counter (0, i)
    for (uint32_t i = 0; i < (uint32_t)Nn; ++i) {
      uint32_t o0, o1; tf2x32(sh, sl, 0u, i, o0, o1); bits[i] = o0 ^ o1;
    }
    for (int i = 0; i < Nn; ++i) pos[i] = i;
    std::stable_sort(pos.begin(), pos.end(),
                     [&](int a, int b) { return bits[a] < bits[b]; });
    std::vector<int> np(Nn);
    for (int i = 0; i < Nn; ++i) np[i] = perm[pos[i]];
    perm.swap(np);
  }
  for (int k = 0; k < Kk; ++k) out12[k] = perm[k];
}

// ---------------------------------------------------------------------------
extern "C" void kernel_launch(void* const* d_in, const int* in_sizes, int n_in,
                              void* d_out, int out_size, void* d_ws, size_t ws_size,
                              hipStream_t stream) {
  const float* x   = (const float*)d_in[0];
  const int*   len = (const int*)d_in[1];
  const float* Wih = (const float*)d_in[2];
  const float* Whh = (const float*)d_in[3];
  const float* bih = (const float*)d_in[4];
  const float* bhh = (const float*)d_in[5];
  const float* w1w = (const float*)d_in[6];
  const float* w1b = (const float*)d_in[7];
  const float* w2w = (const float*)d_in[8];
  const float* w2b = (const float*)d_in[9];
  const float* g1w = (const float*)d_in[10];
  const float* g1b = (const float*)d_in[11];
  const float* g2w = (const float*)d_in[12];
  const float* g2b = (const float*)d_in[13];
  float* out = (float*)d_out;

  float* wsf  = (float*)d_ws;
  float* hfin = wsf;                        // N*H
  float* cent = hfin + (size_t)Nn * Hh;     // K*H
  float* h2g  = cent + Kk * Hh;             // K*H
  float* part = h2g + Kk * Hh;              // 32*K*H
  int*   pcnt = (int*)(part + 32 * Kk * Hh);// 32*K
  float* pkw  = (float*)(pcnt + 32 * Kk);   // 64*6*256*4 = 393216 floats

  IdxArgs ia;
  compute_idx(ia.v);                        // host, deterministic, capture-safe

  pack_w<<<768, 64, 0, stream>>>(Wih, Whh, pkw);
  gru_packed<<<256, 512, 0, stream>>>(x, len, pkw, bih, bhh, hfin);

  km_init<<<1, 256, 0, stream>>>(hfin, cent, ia);
  for (int it = 0; it < MAXIT; ++it) {
    km_assign<<<32, 256, 0, stream>>>(hfin, cent, part, pcnt);
    km_update<<<Kk, 256, 0, stream>>>(part, pcnt, cent);
  }

  gcn<<<1, 256, 0, stream>>>(cent, g1w, g1b, g2w, g2b, h2g);
  finalk<<<Nn, 256, 0, stream>>>(hfin, cent, h2g, w1w, w1b, w2w, w2b, out);
}

// Round 8
// 6494.585 us; speedup vs baseline: 3.1193x; 1.3605x over previous
//
#include <hip/hip_runtime.h>
#include <hip/hip_cooperative_groups.h>
#include <cstdint>
#include <cstring>
#include <vector>
#include <algorithm>

namespace cg = cooperative_groups;

// ---------------------------------------------------------------------------
// GRASPLayer round 8:
//  - GRU k-split: 512 thr/block, thread (c,half) accumulates half the k-range;
//    W read exactly once per CU per step (L1-return-balanced), reg prefetch.
//  - Cooperative kmeans (r4 indexing bug fixed: wave owns 8 of 32 rows),
//    fixed-point early exit, 201 dispatches -> 1.
// ---------------------------------------------------------------------------

namespace {
constexpr int Nn = 2048;
constexpr int Tt = 128;
constexpr int Dd = 256;
constexpr int Hh = 256;
constexpr int Kk = 12;
constexpr int MAXIT = 100;
}

struct IdxArgs { int v[Kk]; };

__device__ __forceinline__ float sigm(float x) { return 1.0f / (1.0f + expf(-x)); }

// ---------------------------------------------------------------------------
// Pack Wih/Whh [3*256 x 256] into pk[k4][w][c][4], w in {ihr,ihz,ihn,hhr,hhz,hhn}.
__global__ __launch_bounds__(64) void pack_w(
    const float* __restrict__ Wih, const float* __restrict__ Whh,
    float* __restrict__ pk)
{
  const int j = blockIdx.x;            // 0..767 = w-row (g*256 + c)
  const int k4 = threadIdx.x;          // 0..63
  const int g = j >> 8, c = j & 255;
  float4 vih = *(const float4*)&Wih[(size_t)j * 256 + k4 * 4];
  float4 vhh = *(const float4*)&Whh[(size_t)j * 256 + k4 * 4];
  *(float4*)&pk[(((size_t)k4 * 6 + g) * 256 + c) * 4]       = vih;
  *(float4*)&pk[(((size_t)k4 * 6 + 3 + g) * 256 + c) * 4]   = vhh;
}

// ---------------------------------------------------------------------------
// 256 blocks x 512 threads; block owns 8 rows. Thread (c, hf) accumulates
// k in [hf*128, hf*128+128) for column c, all 8 rows. Partials combined via
// LDS each step; hf==0 threads apply gates. W bytes/CU/step = 1.5MB (once).
__global__ __launch_bounds__(512, 1) void gru_ks(
    const float* __restrict__ x, const int* __restrict__ len,
    const float* __restrict__ pk,
    const float* __restrict__ bih, const float* __restrict__ bhh,
    float* __restrict__ hfin)
{
  __shared__ alignas(16) float xls[8][260];
  __shared__ alignas(16) float hls[8][260];
  __shared__ alignas(16) float pbuf[4][8][256];     // partner partials
  const int tid = threadIdx.x;
  const int C = tid & 255;
  const int hf = tid >> 8;                           // k-half
  const int n0 = blockIdx.x * 8;

  const float bi_r = bih[C],          bh_r = bhh[C];
  const float bi_z = bih[Hh + C],     bh_z = bhh[Hh + C];
  const float bi_n = bih[2 * Hh + C], bh_n = bhh[2 * Hh + C];
  int L[8];
  #pragma unroll
  for (int r = 0; r < 8; ++r) L[r] = len[n0 + r];

  // per-half W base: k4 in [hf*32, hf*32+32)
  const float* __restrict__ p0 = pk + (size_t)C * 4 + (size_t)hf * 32 * 6144;

  if (hf == 0) {
    #pragma unroll
    for (int r = 0; r < 8; ++r) hls[r][C] = 0.f;
  }

  for (int t = 0; t < Tt; ++t) {
    // stage x_t (512 f4, one per thread, coalesced)
    {
      int row = tid >> 6, c4 = tid & 63;
      *(float4*)&xls[row][c4 * 4] =
          *(const float4*)&x[(size_t)(n0 + row) * (Tt * Dd) + (size_t)t * Dd + c4 * 4];
    }
    __syncthreads();   // orders: x stage, hls init/updates, pbuf reuse

    float aR[8] = {}, aZ[8] = {}, aXN[8] = {}, aHN[8] = {};

    // ---- phase A: gx partial over this k-half (k ascending) ----
    {
      const float* pp = p0;
      float4 wr = *(const float4*)(pp);
      float4 wz = *(const float4*)(pp + 1024);
      float4 wn = *(const float4*)(pp + 2048);
      #pragma unroll 2
      for (int k4 = 0; k4 < 32; ++k4) {
        const float* pn = (k4 < 31) ? (pp + 6144) : pp;   // clamped prefetch
        float4 nr = *(const float4*)(pn);
        float4 nz = *(const float4*)(pn + 1024);
        float4 nn = *(const float4*)(pn + 2048);
        const int k = hf * 128 + k4 * 4;
        #pragma unroll
        for (int r = 0; r < 8; ++r) {
          float4 xv = *(const float4*)&xls[r][k];     // broadcast
          aR[r]  += xv.x * wr.x; aR[r]  += xv.y * wr.y;
          aR[r]  += xv.z * wr.z; aR[r]  += xv.w * wr.w;
          aZ[r]  += xv.x * wz.x; aZ[r]  += xv.y * wz.y;
          aZ[r]  += xv.z * wz.z; aZ[r]  += xv.w * wz.w;
          aXN[r] += xv.x * wn.x; aXN[r] += xv.y * wn.y;
          aXN[r] += xv.z * wn.z; aXN[r] += xv.w * wn.w;
        }
        wr = nr; wz = nz; wn = nn; pp = pn;
      }
    }
    // ---- phase B: gh partial over this k-half ----
    {
      const float* pp = p0 + 3072;
      float4 wr = *(const float4*)(pp);
      float4 wz = *(const float4*)(pp + 1024);
      float4 wn = *(const float4*)(pp + 2048);
      #pragma unroll 2
      for (int k4 = 0; k4 < 32; ++k4) {
        const float* pn = (k4 < 31) ? (pp + 6144) : pp;
        float4 nr = *(const float4*)(pn);
        float4 nz = *(const float4*)(pn + 1024);
        float4 nn = *(const float4*)(pn + 2048);
        const int k = hf * 128 + k4 * 4;
        #pragma unroll
        for (int r = 0; r < 8; ++r) {
          float4 hv = *(const float4*)&hls[r][k];     // broadcast
          aR[r]  += hv.x * wr.x; aR[r]  += hv.y * wr.y;
          aR[r]  += hv.z * wr.z; aR[r]  += hv.w * wr.w;
          aZ[r]  += hv.x * wz.x; aZ[r]  += hv.y * wz.y;
          aZ[r]  += hv.z * wz.z; aZ[r]  += hv.w * wz.w;
          aHN[r] += hv.x * wn.x; aHN[r] += hv.y * wn.y;
          aHN[r] += hv.z * wn.z; aHN[r] += hv.w * wn.w;
        }
        wr = nr; wz = nz; wn = nn; pp = pn;
      }
    }

    // ---- export hf==1 partials ----
    if (hf == 1) {
      #pragma unroll
      for (int r = 0; r < 8; ++r) {
        pbuf[0][r][C] = aR[r];  pbuf[1][r][C] = aZ[r];
        pbuf[2][r][C] = aXN[r]; pbuf[3][r][C] = aHN[r];
      }
    }
    __syncthreads();

    // ---- combine + gates (hf==0 only); order r,z,n (PyTorch layout) ----
    if (hf == 0) {
      #pragma unroll
      for (int r = 0; r < 8; ++r) {
        if (t < L[r]) {
          float sR  = aR[r]  + pbuf[0][r][C];
          float sZ  = aZ[r]  + pbuf[1][r][C];
          float sXN = aXN[r] + pbuf[2][r][C];
          float sHN = aHN[r] + pbuf[3][r][C];
          float rg = sigm(sR + bi_r + bh_r);
          float zg = sigm(sZ + bi_z + bh_z);
          float ng = tanhf(sXN + bi_n + rg * (sHN + bh_n));
          float hv = (1.f - zg) * ng + zg * hls[r][C];
          hls[r][C] = hv;
          if (t == L[r] - 1) hfin[(size_t)(n0 + r) * Hh + C] = hv;
        }
      }
    }
    // next iteration's top __syncthreads orders hls writes before reads
  }
}

// ---------------------------------------------------------------------------
// Cooperative kmeans: 64 blocks x 256 threads, 32 rows/block (wave owns 8).
// All 100 iters in one launch; fixed-point early exit (codes unchanged =>
// centers bitwise unchanged => remaining iters are no-ops).
__global__ __launch_bounds__(256, 1) void km_coop(
    const float* __restrict__ hfin, float* __restrict__ cent,
    float* __restrict__ part, int* __restrict__ pcnt,
    int* __restrict__ gflag, IdxArgs ia)
{
  __shared__ alignas(16) float rows_l[32][260];
  __shared__ alignas(16) float cs[Kk][260];
  __shared__ float psl[Kk][256];
  __shared__ float c2s[Kk];
  __shared__ int codes_l[32];
  __shared__ int pcl[Kk];
  __shared__ int chg_l, brk_l;
  cg::grid_group grid = cg::this_grid();
  const int tid = threadIdx.x, lane = tid & 63, w = tid >> 6;
  const int blk = blockIdx.x, n0 = blk * 32;

  // rows -> LDS (2048 f4, 8 per thread)
  #pragma unroll
  for (int i = 0; i < 8; ++i) {
    int f = tid + i * 256;
    int row = f >> 6, c4 = f & 63;
    *(float4*)&rows_l[row][c4 * 4] =
        *(const float4*)&hfin[(size_t)(n0 + row) * Hh + c4 * 4];
  }
  if (tid < 32) codes_l[tid] = -1;
  if (blk == 0) {
    if (tid == 0) { gflag[0] = 0; gflag[1] = 0; }
    #pragma unroll
    for (int i = 0; i < 3; ++i) {            // initial centers (empty-keep path)
      int f = tid + i * 256;
      int k = f >> 6, c4 = f & 63;
      *(float4*)&cent[(size_t)k * Hh + c4 * 4] =
          *(const float4*)&hfin[(size_t)ia.v[k] * Hh + c4 * 4];
    }
  }
  __syncthreads();
  float4 v4[8];                               // wave w owns rows w*8 .. w*8+7
  #pragma unroll
  for (int rr = 0; rr < 8; ++rr)
    v4[rr] = *(const float4*)&rows_l[w * 8 + rr][lane * 4];
  __threadfence();
  grid.sync();                                // flags/cent init visible

  for (int it = 0; it < MAXIT; ++it) {
    // centers -> LDS
    #pragma unroll
    for (int i = 0; i < 3; ++i) {
      int f = tid + i * 256;
      int k = f >> 6, c4 = f & 63;
      float4 cv = (it == 0)
          ? *(const float4*)&hfin[(size_t)ia.v[k] * Hh + c4 * 4]
          : *(const float4*)&cent[(size_t)k * Hh + c4 * 4];
      *(float4*)&cs[k][c4 * 4] = cv;
    }
    if (tid == 0) chg_l = 0;
    if (tid < Kk) pcl[tid] = 0;
    __syncthreads();
    if (tid < Kk) {                           // serial |c|^2, verbatim r3 order
      float s = 0.f;
      for (int c = 0; c < Hh; ++c) { float v = cs[tid][c]; s += v * v; }
      c2s[tid] = s;
    }
    __syncthreads();

    // assign (strict <: first-min = argmin), wave-parallel dot via shuffle
    int mych = 0;
    #pragma unroll
    for (int rr = 0; rr < 8; ++rr) {
      const int row = w * 8 + rr;
      float best = 3.4e38f; int bi = 0;
      #pragma unroll
      for (int k = 0; k < Kk; ++k) {
        float4 cv = *(const float4*)&cs[k][lane * 4];
        float p = v4[rr].x * cv.x + v4[rr].y * cv.y
                + v4[rr].z * cv.z + v4[rr].w * cv.w;
        #pragma unroll
        for (int m = 1; m < 64; m <<= 1) p += __shfl_xor(p, m, 64);
        float d = c2s[k] - 2.f * p;
        if (d < best) { best = d; bi = k; }
      }
      if (lane == 0) {
        if (bi != codes_l[row]) mych = 1;
        codes_l[row] = bi;
      }
    }
    if (mych) atomicOr(&chg_l, 1);
    __syncthreads();

    // per-column partial sums in fixed row order (column-private: no races)
    #pragma unroll
    for (int k = 0; k < Kk; ++k) psl[k][tid] = 0.f;
    for (int r = 0; r < 32; ++r)
      psl[codes_l[r]][tid] += rows_l[r][tid];
    if (tid < 32) atomicAdd(&pcl[codes_l[tid]], 1);
    if (tid == 0 && chg_l) atomicOr(&gflag[it & 1], 1);
    __syncthreads();
    #pragma unroll
    for (int k = 0; k < Kk; ++k)
      part[((size_t)blk * Kk + k) * Hh + tid] = psl[k][tid];
    if (tid < Kk) pcnt[blk * Kk + tid] = pcl[tid];
    __threadfence();
    grid.sync();

    // update: blocks 0..11, fixed-order reduction; empty cluster keeps old
    if (blk < Kk) {
      float s = 0.f;
      for (int p = 0; p < 64; ++p) s += part[((size_t)p * Kk + blk) * Hh + tid];
      int cn = 0;
      for (int p = 0; p < 64; ++p) cn += pcnt[p * Kk + blk];
      if (cn > 0) cent[(size_t)blk * Hh + tid] = s / (float)cn;
    }
    if (blk == 0 && tid == 0) gflag[(it + 1) & 1] = 0;   // reset next slot
    __threadfence();
    grid.sync();
    if (tid == 0) brk_l = atomicAdd(&gflag[it & 1], 0);  // coherent read
    __syncthreads();
    if (brk_l == 0) break;                    // Lloyd fixed point
  }
}

// ---------------------------------------------------------------------------
// h1 = relu(centers@g1_w + g1_b); h2 = relu(h1@g2_w + g2_b). One block.
__global__ __launch_bounds__(256) void gcn(
    const float* __restrict__ cent, const float* __restrict__ g1w,
    const float* __restrict__ g1b, const float* __restrict__ g2w,
    const float* __restrict__ g2b, float* __restrict__ h2out)
{
  __shared__ float a[Kk][Hh];
  __shared__ float b[Kk][Hh];
  int c = threadIdx.x;
  for (int i = c; i < Kk * Hh; i += 256) ((float*)a)[i] = cent[i];
  __syncthreads();
  float acc[Kk];
  #pragma unroll
  for (int k = 0; k < Kk; ++k) acc[k] = 0.f;
  for (int j = 0; j < Hh; ++j) {
    float wv = g1w[(size_t)j * Hh + c];
    #pragma unroll
    for (int k = 0; k < Kk; ++k) acc[k] += a[k][j] * wv;
  }
  #pragma unroll
  for (int k = 0; k < Kk; ++k) b[k][c] = fmaxf(acc[k] + g1b[c], 0.f);
  __syncthreads();
  #pragma unroll
  for (int k = 0; k < Kk; ++k) acc[k] = 0.f;
  for (int j = 0; j < Hh; ++j) {
    float wv = g2w[(size_t)j * Hh + c];
    #pragma unroll
    for (int k = 0; k < Kk; ++k) acc[k] += b[k][j] * wv;
  }
  #pragma unroll
  for (int k = 0; k < Kk; ++k) h2out[k * Hh + c] = fmaxf(acc[k] + g2b[c], 0.f);
}

// scores = softmax(relu(ht@centers^T)); clu = scores@h2; gated blend. 1 block/row.
__global__ __launch_bounds__(256) void finalk(
    const float* __restrict__ hfin, const float* __restrict__ cent,
    const float* __restrict__ h2, const float* __restrict__ w1w,
    const float* __restrict__ w1b, const float* __restrict__ w2w,
    const float* __restrict__ w2b, float* __restrict__ out)
{
  __shared__ alignas(16) float cs[Kk][Hh];
  __shared__ alignas(16) float hs[Kk][Hh];
  __shared__ float red[4];
  const int tid = threadIdx.x, lane = tid & 63, w = tid >> 6;
  const int n = blockIdx.x;
  for (int i = tid; i < Kk * Hh; i += 256) { ((float*)cs)[i] = cent[i]; ((float*)hs)[i] = h2[i]; }
  float ht = hfin[(size_t)n * Hh + tid];
  __syncthreads();

  auto bred = [&](float v) -> float {
    #pragma unroll
    for (int m = 1; m < 64; m <<= 1) v += __shfl_xor(v, m, 64);
    __syncthreads();
    if (lane == 0) red[w] = v;
    __syncthreads();
    return red[0] + red[1] + red[2] + red[3];
  };

  float ev[Kk];
  #pragma unroll
  for (int k = 0; k < Kk; ++k)
    ev[k] = fmaxf(bred(ht * cs[k][tid]), 0.f);

  float mx = ev[0];
  #pragma unroll
  for (int k = 1; k < Kk; ++k) mx = fmaxf(mx, ev[k]);
  float se = 0.f; float sc[Kk];
  #pragma unroll
  for (int k = 0; k < Kk; ++k) { sc[k] = expf(ev[k] - mx); se += sc[k]; }
  float inv = 1.f / se;
  float clu = 0.f;
  #pragma unroll
  for (int k = 0; k < Kk; ++k) clu += sc[k] * inv * hs[k][tid];

  float r1 = bred(clu * w1w[tid]);
  float r2 = bred(ht * w2w[tid]);
  float a1 = sigm(r1 + w1b[0]);
  float a2 = sigm(r2 + w2b[0]);
  float wn = a1 / (a1 + a2);
  out[(size_t)n * Hh + tid] = wn * clu + (1.f - wn) * ht;
}

// ---------------------------------------------------------------------------
// Host-side threefry2x32 (JAX), reproducing jax.random.permutation(key(42), 2048)[:12].
static void tf2x32(uint32_t k0, uint32_t k1, uint32_t c0, uint32_t c1,
                   uint32_t& o0, uint32_t& o1) {
  uint32_t ks2 = k0 ^ k1 ^ 0x1BD11BDAu;
  uint32_t x0 = c0 + k0, x1 = c1 + k1;
#define TFR(r) do { x0 += x1; x1 = (x1 << (r)) | (x1 >> (32 - (r))); x1 ^= x0; } while (0)
  TFR(13); TFR(15); TFR(26); TFR(6);
  x0 += k1;  x1 += ks2 + 1u;
  TFR(17); TFR(29); TFR(16); TFR(24);
  x0 += ks2; x1 += k0 + 2u;
  TFR(13); TFR(15); TFR(26); TFR(6);
  x0 += k0;  x1 += k1 + 3u;
  TFR(17); TFR(29); TFR(16); TFR(24);
  x0 += k1;  x1 += ks2 + 4u;
  TFR(13); TFR(15); TFR(26); TFR(6);
  x0 += ks2; x1 += k0 + 5u;
#undef TFR
  o0 = x0; o1 = x1;
}

static void compute_idx(int* out12) {
  uint32_t kh = 0u, kl = 42u;     // jax.random.key(42) -> (0, 42)
  std::vector<int> perm(Nn);
  for (int i = 0; i < Nn; ++i) perm[i] = i;
  std::vector<uint32_t> bits(Nn);
  std::vector<int> pos(Nn);
  for (int round = 0; round < 2; ++round) {     // 2 rounds for n=2048
    uint32_t nh, nl, sh, sl;
    tf2x32(kh, kl, 0u, 0u, nh, nl);             // split: counters (0,0),(0,1)
    tf2x32(kh, kl, 0u, 1u, sh, sl);
    kh = nh; kl = nl;
    // partitionable random_bits(32): bits[i] = o0 ^ o1 at counter (0, i)
    for (uint32_t i = 0; i < (uint32_t)Nn; ++i) {
      uint32_t o0, o1; tf2x32(sh, sl, 0u, i, o0, o1); bits[i] = o0 ^ o1;
    }
    for (int i = 0; i < Nn; ++i) pos[i] = i;
    std::stable_sort(pos.begin(), pos.end(),
                     [&](int a, int b) { return bits[a] < bits[b]; });
    std::vector<int> np(Nn);
    for (int i = 0; i < Nn; ++i) np[i] = perm[pos[i]];
    perm.swap(np);
  }
  for (int k = 0; k < Kk; ++k) out12[k] = perm[k];
}

// ---------------------------------------------------------------------------
extern "C" void kernel_launch(void* const* d_in, const int* in_sizes, int n_in,
                              void* d_out, int out_size, void* d_ws, size_t ws_size,
                              hipStream_t stream) {
  const float* x   = (const float*)d_in[0];
  const int*   len = (const int*)d_in[1];
  const float* Wih = (const float*)d_in[2];
  const float* Whh = (const float*)d_in[3];
  const float* bih = (const float*)d_in[4];
  const float* bhh = (const float*)d_in[5];
  const float* w1w = (const float*)d_in[6];
  const float* w1b = (const float*)d_in[7];
  const float* w2w = (const float*)d_in[8];
  const float* w2b = (const float*)d_in[9];
  const float* g1w = (const float*)d_in[10];
  const float* g1b = (const float*)d_in[11];
  const float* g2w = (const float*)d_in[12];
  const float* g2b = (const float*)d_in[13];
  float* out = (float*)d_out;

  float* wsf  = (float*)d_ws;
  float* hfin = wsf;                          // N*H           = 524288 f
  float* cent = hfin + (size_t)Nn * Hh;       // K*H           = 3072 f
  float* h2g  = cent + Kk * Hh;               // K*H           = 3072 f
  float* part = h2g + Kk * Hh;                // 64*K*H        = 196608 f
  int*   pcnt = (int*)(part + 64 * Kk * Hh);  // 64*K ints (pad to 1024)
  int*   gflag = pcnt + 768;                  // 2 ints
  float* pkw  = (float*)(pcnt + 1024);        // 64*6*256*4    = 393216 f (16B-aligned)

  IdxArgs ia;
  compute_idx(ia.v);                          // host, deterministic, capture-safe

  pack_w<<<768, 64, 0, stream>>>(Wih, Whh, pkw);
  gru_ks<<<256, 512, 0, stream>>>(x, len, pkw, bih, bhh, hfin);

  {
    void* ka[] = {(void*)&hfin, (void*)&cent, (void*)&part, (void*)&pcnt,
                  (void*)&gflag, (void*)&ia};
    hipLaunchCooperativeKernel((const void*)km_coop, dim3(64), dim3(256),
                               ka, 0, stream);
  }

  gcn<<<1, 256, 0, stream>>>(cent, g1w, g1b, g2w, g2b, h2g);
  finalk<<<Nn, 256, 0, stream>>>(hfin, cent, h2g, w1w, w1b, w2w, w2b, out);
}

// Round 10
// 5566.758 us; speedup vs baseline: 3.6392x; 1.1667x over previous
//
#include <hip/hip_runtime.h>
#include <hip/hip_cooperative_groups.h>
#include <cstdint>
#include <cstring>
#include <vector>
#include <algorithm>

namespace cg = cooperative_groups;

// ---------------------------------------------------------------------------
// GRASPLayer round 10 (= round 9 with the FMA4 macro-capture bug fixed):
//  - GRU "2-col x k-quarter" layout: 512 thr/block, thread owns cols (cp,cp+128)
//    and k in [q*64,(q+1)*64). Same FMA count, HALF the LDS broadcast reads
//    (24 FMAs per ds_read_b128). Tree combine of 4 k-partials via LDS float4.
//  - kmeans/gcn/finalk/pack_w verbatim from round-8 PASS.
// ---------------------------------------------------------------------------

namespace {
constexpr int Nn = 2048;
constexpr int Tt = 128;
constexpr int Dd = 256;
constexpr int Hh = 256;
constexpr int Kk = 12;
constexpr int MAXIT = 100;
}

struct IdxArgs { int v[Kk]; };

__device__ __forceinline__ float sigm(float x) { return 1.0f / (1.0f + expf(-x)); }

// NOTE: parameters uppercase so member tokens .x/.y/.z/.w can't be captured.
#define FMA4(A, V, W) do { A += (V).x*(W).x; A += (V).y*(W).y; \
                           A += (V).z*(W).z; A += (V).w*(W).w; } while (0)

// ---------------------------------------------------------------------------
// Pack Wih/Whh [3*256 x 256] into pk[k4][g][c][4], g in {ihr,ihz,ihn,hhr,hhz,hhn}.
__global__ __launch_bounds__(64) void pack_w(
    const float* __restrict__ Wih, const float* __restrict__ Whh,
    float* __restrict__ pk)
{
  const int j = blockIdx.x;            // 0..767 = w-row (g*256 + c)
  const int k4 = threadIdx.x;          // 0..63
  const int g = j >> 8, c = j & 255;
  float4 vih = *(const float4*)&Wih[(size_t)j * 256 + k4 * 4];
  float4 vhh = *(const float4*)&Whh[(size_t)j * 256 + k4 * 4];
  *(float4*)&pk[(((size_t)k4 * 6 + g) * 256 + c) * 4]       = vih;
  *(float4*)&pk[(((size_t)k4 * 6 + 3 + g) * 256 + c) * 4]   = vhh;
}

// ---------------------------------------------------------------------------
// 256 blocks x 512 threads; block owns 8 rows. Thread (cp, q) accumulates
// cols {cp, cp+128} over k-quarter q. Combine via LDS tree; q==0 applies gates.
__global__ __launch_bounds__(512, 1) void gru_q(
    const float* __restrict__ x, const int* __restrict__ len,
    const float* __restrict__ pk,
    const float* __restrict__ bih, const float* __restrict__ bhh,
    float* __restrict__ hfin)
{
  __shared__ alignas(16) float xls[8][260];
  __shared__ alignas(16) float hls[8][260];
  __shared__ float4 pbuf[2][8][256];            // 64 KB combine buffer
  const int tid = threadIdx.x;
  const int cp = tid & 127;                     // columns cp, cp+128
  const int q  = tid >> 7;                      // k-quarter
  const int n0 = blockIdx.x * 8;
  const int C0 = cp, C1 = cp + 128;

  const float bir0 = bih[C0], bhr0 = bhh[C0];
  const float biz0 = bih[Hh + C0], bhz0 = bhh[Hh + C0];
  const float bin0 = bih[2 * Hh + C0], bhn0 = bhh[2 * Hh + C0];
  const float bir1 = bih[C1], bhr1 = bhh[C1];
  const float biz1 = bih[Hh + C1], bhz1 = bhh[Hh + C1];
  const float bin1 = bih[2 * Hh + C1], bhn1 = bhh[2 * Hh + C1];
  int L[8];
  #pragma unroll
  for (int r = 0; r < 8; ++r) L[r] = len[n0 + r];

  const int q16 = q * 16;
  const size_t cp4 = (size_t)cp * 4;

  if (tid < 256) {
    #pragma unroll
    for (int r = 0; r < 8; ++r) hls[r][tid] = 0.f;
  }

  for (int t = 0; t < Tt; ++t) {
    // stage x_t (512 float4, coalesced)
    {
      int row = tid >> 6, c4 = tid & 63;
      *(float4*)&xls[row][c4 * 4] =
          *(const float4*)&x[(size_t)(n0 + row) * (Tt * Dd) + (size_t)t * Dd + c4 * 4];
    }
    __syncthreads();   // orders x stage + hls updates + pbuf reuse

    float aR[8][2] = {}, aZ[8][2] = {}, aXN[8][2] = {}, aHN[8][2] = {};

    // ---- phase A: gx partials over k-quarter (k ascending) ----
    #pragma unroll 1
    for (int i = 0; i < 16; ++i) {
      const int k4 = q16 + i;
      const float* pb = pk + (size_t)k4 * 6144 + cp4;
      float4 wr0 = *(const float4*)(pb);
      float4 wr1 = *(const float4*)(pb + 512);
      float4 wz0 = *(const float4*)(pb + 1024);
      float4 wz1 = *(const float4*)(pb + 1536);
      float4 wn0 = *(const float4*)(pb + 2048);
      float4 wn1 = *(const float4*)(pb + 2560);
      const int k = k4 * 4;
      #pragma unroll
      for (int r = 0; r < 8; ++r) {
        float4 xv = *(const float4*)&xls[r][k];   // broadcast
        FMA4(aR[r][0],  xv, wr0); FMA4(aR[r][1],  xv, wr1);
        FMA4(aZ[r][0],  xv, wz0); FMA4(aZ[r][1],  xv, wz1);
        FMA4(aXN[r][0], xv, wn0); FMA4(aXN[r][1], xv, wn1);
      }
    }
    // ---- phase B: gh partials over k-quarter ----
    #pragma unroll 1
    for (int i = 0; i < 16; ++i) {
      const int k4 = q16 + i;
      const float* pb = pk + (size_t)k4 * 6144 + 3072 + cp4;
      float4 wr0 = *(const float4*)(pb);
      float4 wr1 = *(const float4*)(pb + 512);
      float4 wz0 = *(const float4*)(pb + 1024);
      float4 wz1 = *(const float4*)(pb + 1536);
      float4 wn0 = *(const float4*)(pb + 2048);
      float4 wn1 = *(const float4*)(pb + 2560);
      const int k = k4 * 4;
      #pragma unroll
      for (int r = 0; r < 8; ++r) {
        float4 hv = *(const float4*)&hls[r][k];   // broadcast
        FMA4(aR[r][0],  hv, wr0); FMA4(aR[r][1],  hv, wr1);
        FMA4(aZ[r][0],  hv, wz0); FMA4(aZ[r][1],  hv, wz1);
        FMA4(aHN[r][0], hv, wn0); FMA4(aHN[r][1], hv, wn1);
      }
    }

    // ---- combine tree: (q0+=q1, q2+=q3) then q0 += q2' ----
    if (q == 1 || q == 3) {
      const int reg = q >> 1;
      #pragma unroll
      for (int r = 0; r < 8; ++r) {
        pbuf[reg][r][C0] = make_float4(aR[r][0], aZ[r][0], aXN[r][0], aHN[r][0]);
        pbuf[reg][r][C1] = make_float4(aR[r][1], aZ[r][1], aXN[r][1], aHN[r][1]);
      }
    }
    __syncthreads();
    if (q == 0 || q == 2) {
      const int reg = q >> 1;
      #pragma unroll
      for (int r = 0; r < 8; ++r) {
        float4 p0 = pbuf[reg][r][C0];
        float4 p1 = pbuf[reg][r][C1];
        aR[r][0] += p0.x; aZ[r][0] += p0.y; aXN[r][0] += p0.z; aHN[r][0] += p0.w;
        aR[r][1] += p1.x; aZ[r][1] += p1.y; aXN[r][1] += p1.z; aHN[r][1] += p1.w;
      }
    }
    __syncthreads();
    if (q == 2) {
      #pragma unroll
      for (int r = 0; r < 8; ++r) {
        pbuf[0][r][C0] = make_float4(aR[r][0], aZ[r][0], aXN[r][0], aHN[r][0]);
        pbuf[0][r][C1] = make_float4(aR[r][1], aZ[r][1], aXN[r][1], aHN[r][1]);
      }
    }
    __syncthreads();

    // ---- gates (q==0 threads; order r,z,n, PyTorch layout) ----
    if (q == 0) {
      #pragma unroll
      for (int r = 0; r < 8; ++r) {
        if (t < L[r]) {
          float4 p0 = pbuf[0][r][C0];
          float4 p1 = pbuf[0][r][C1];
          float sR0 = aR[r][0] + p0.x, sZ0 = aZ[r][0] + p0.y;
          float sX0 = aXN[r][0] + p0.z, sH0 = aHN[r][0] + p0.w;
          float sR1 = aR[r][1] + p1.x, sZ1 = aZ[r][1] + p1.y;
          float sX1 = aXN[r][1] + p1.z, sH1 = aHN[r][1] + p1.w;
          float rg0 = sigm(sR0 + bir0 + bhr0);
          float zg0 = sigm(sZ0 + biz0 + bhz0);
          float ng0 = tanhf(sX0 + bin0 + rg0 * (sH0 + bhn0));
          float hv0 = (1.f - zg0) * ng0 + zg0 * hls[r][C0];
          float rg1 = sigm(sR1 + bir1 + bhr1);
          float zg1 = sigm(sZ1 + biz1 + bhz1);
          float ng1 = tanhf(sX1 + bin1 + rg1 * (sH1 + bhn1));
          float hv1 = (1.f - zg1) * ng1 + zg1 * hls[r][C1];
          hls[r][C0] = hv0;
          hls[r][C1] = hv1;
          if (t == L[r] - 1) {
            hfin[(size_t)(n0 + r) * Hh + C0] = hv0;
            hfin[(size_t)(n0 + r) * Hh + C1] = hv1;
          }
        }
      }
    }
    // next iteration's top __syncthreads orders hls/pbuf reuse
  }
}

// ---------------------------------------------------------------------------
// Cooperative kmeans (verbatim round-8 PASS): 64 blocks x 256 threads,
// 32 rows/block (wave owns 8); fixed-point early exit.
__global__ __launch_bounds__(256, 1) void km_coop(
    const float* __restrict__ hfin, float* __restrict__ cent,
    float* __restrict__ part, int* __restrict__ pcnt,
    int* __restrict__ gflag, IdxArgs ia)
{
  __shared__ alignas(16) float rows_l[32][260];
  __shared__ alignas(16) float cs[Kk][260];
  __shared__ float psl[Kk][256];
  __shared__ float c2s[Kk];
  __shared__ int codes_l[32];
  __shared__ int pcl[Kk];
  __shared__ int chg_l, brk_l;
  cg::grid_group grid = cg::this_grid();
  const int tid = threadIdx.x, lane = tid & 63, w = tid >> 6;
  const int blk = blockIdx.x, n0 = blk * 32;

  #pragma unroll
  for (int i = 0; i < 8; ++i) {
    int f = tid + i * 256;
    int row = f >> 6, c4 = f & 63;
    *(float4*)&rows_l[row][c4 * 4] =
        *(const float4*)&hfin[(size_t)(n0 + row) * Hh + c4 * 4];
  }
  if (tid < 32) codes_l[tid] = -1;
  if (blk == 0) {
    if (tid == 0) { gflag[0] = 0; gflag[1] = 0; }
    #pragma unroll
    for (int i = 0; i < 3; ++i) {
      int f = tid + i * 256;
      int k = f >> 6, c4 = f & 63;
      *(float4*)&cent[(size_t)k * Hh + c4 * 4] =
          *(const float4*)&hfin[(size_t)ia.v[k] * Hh + c4 * 4];
    }
  }
  __syncthreads();
  float4 v4[8];
  #pragma unroll
  for (int rr = 0; rr < 8; ++rr)
    v4[rr] = *(const float4*)&rows_l[w * 8 + rr][lane * 4];
  __threadfence();
  grid.sync();

  for (int it = 0; it < MAXIT; ++it) {
    #pragma unroll
    for (int i = 0; i < 3; ++i) {
      int f = tid + i * 256;
      int k = f >> 6, c4 = f & 63;
      float4 cv = (it == 0)
          ? *(const float4*)&hfin[(size_t)ia.v[k] * Hh + c4 * 4]
          : *(const float4*)&cent[(size_t)k * Hh + c4 * 4];
      *(float4*)&cs[k][c4 * 4] = cv;
    }
    if (tid == 0) chg_l = 0;
    if (tid < Kk) pcl[tid] = 0;
    __syncthreads();
    if (tid < Kk) {
      float s = 0.f;
      for (int c = 0; c < Hh; ++c) { float v = cs[tid][c]; s += v * v; }
      c2s[tid] = s;
    }
    __syncthreads();

    int mych = 0;
    #pragma unroll
    for (int rr = 0; rr < 8; ++rr) {
      const int row = w * 8 + rr;
      float best = 3.4e38f; int bi = 0;
      #pragma unroll
      for (int k = 0; k < Kk; ++k) {
        float4 cv = *(const float4*)&cs[k][lane * 4];
        float p = v4[rr].x * cv.x + v4[rr].y * cv.y
                + v4[rr].z * cv.z + v4[rr].w * cv.w;
        #pragma unroll
        for (int m = 1; m < 64; m <<= 1) p += __shfl_xor(p, m, 64);
        float d = c2s[k] - 2.f * p;
        if (d < best) { best = d; bi = k; }
      }
      if (lane == 0) {
        if (bi != codes_l[row]) mych = 1;
        codes_l[row] = bi;
      }
    }
    if (mych) atomicOr(&chg_l, 1);
    __syncthreads();

    #pragma unroll
    for (int k = 0; k < Kk; ++k) psl[k][tid] = 0.f;
    for (int r = 0; r < 32; ++r)
      psl[codes_l[r]][tid] += rows_l[r][tid];
    if (tid < 32) atomicAdd(&pcl[codes_l[tid]], 1);
    if (tid == 0 && chg_l) atomicOr(&gflag[it & 1], 1);
    __syncthreads();
    #pragma unroll
    for (int k = 0; k < Kk; ++k)
      part[((size_t)blk * Kk + k) * Hh + tid] = psl[k][tid];
    if (tid < Kk) pcnt[blk * Kk + tid] = pcl[tid];
    __threadfence();
    grid.sync();

    if (blk < Kk) {
      float s = 0.f;
      for (int p = 0; p < 64; ++p) s += part[((size_t)p * Kk + blk) * Hh + tid];
      int cn = 0;
      for (int p = 0; p < 64; ++p) cn += pcnt[p * Kk + blk];
      if (cn > 0) cent[(size_t)blk * Hh + tid] = s / (float)cn;
    }
    if (blk == 0 && tid == 0) gflag[(it + 1) & 1] = 0;
    __threadfence();
    grid.sync();
    if (tid == 0) brk_l = atomicAdd(&gflag[it & 1], 0);
    __syncthreads();
    if (brk_l == 0) break;
  }
}

// ---------------------------------------------------------------------------
// h1 = relu(centers@g1_w + g1_b); h2 = relu(h1@g2_w + g2_b). One block.
__global__ __launch_bounds__(256) void gcn(
    const float* __restrict__ cent, const float* __restrict__ g1w,
    const float* __restrict__ g1b, const float* __restrict__ g2w,
    const float* __restrict__ g2b, float* __restrict__ h2out)
{
  __shared__ float a[Kk][Hh];
  __shared__ float b[Kk][Hh];
  int c = threadIdx.x;
  for (int i = c; i < Kk * Hh; i += 256) ((float*)a)[i] = cent[i];
  __syncthreads();
  float acc[Kk];
  #pragma unroll
  for (int k = 0; k < Kk; ++k) acc[k] = 0.f;
  for (int j = 0; j < Hh; ++j) {
    float wv = g1w[(size_t)j * Hh + c];
    #pragma unroll
    for (int k = 0; k < Kk; ++k) acc[k] += a[k][j] * wv;
  }
  #pragma unroll
  for (int k = 0; k < Kk; ++k) b[k][c] = fmaxf(acc[k] + g1b[c], 0.f);
  __syncthreads();
  #pragma unroll
  for (int k = 0; k < Kk; ++k) acc[k] = 0.f;
  for (int j = 0; j < Hh; ++j) {
    float wv = g2w[(size_t)j * Hh + c];
    #pragma unroll
    for (int k = 0; k < Kk; ++k) acc[k] += b[k][j] * wv;
  }
  #pragma unroll
  for (int k = 0; k < Kk; ++k) h2out[k * Hh + c] = fmaxf(acc[k] + g2b[c], 0.f);
}

// scores = softmax(relu(ht@centers^T)); clu = scores@h2; gated blend. 1 block/row.
__global__ __launch_bounds__(256) void finalk(
    const float* __restrict__ hfin, const float* __restrict__ cent,
    const float* __restrict__ h2, const float* __restrict__ w1w,
    const float* __restrict__ w1b, const float* __restrict__ w2w,
    const float* __restrict__ w2b, float* __restrict__ out)
{
  __shared__ alignas(16) float cs[Kk][Hh];
  __shared__ alignas(16) float hs[Kk][Hh];
  __shared__ float red[4];
  const int tid = threadIdx.x, lane = tid & 63, w = tid >> 6;
  const int n = blockIdx.x;
  for (int i = tid; i < Kk * Hh; i += 256) { ((float*)cs)[i] = cent[i]; ((float*)hs)[i] = h2[i]; }
  float ht = hfin[(size_t)n * Hh + tid];
  __syncthreads();

  auto bred = [&](float v) -> float {
    #pragma unroll
    for (int m = 1; m < 64; m <<= 1) v += __shfl_xor(v, m, 64);
    __syncthreads();
    if (lane == 0) red[w] = v;
    __syncthreads();
    return red[0] + red[1] + red[2] + red[3];
  };

  float ev[Kk];
  #pragma unroll
  for (int k = 0; k < Kk; ++k)
    ev[k] = fmaxf(bred(ht * cs[k][tid]), 0.f);

  float mx = ev[0];
  #pragma unroll
  for (int k = 1; k < Kk; ++k) mx = fmaxf(mx, ev[k]);
  float se = 0.f; float sc[Kk];
  #pragma unroll
  for (int k = 0; k < Kk; ++k) { sc[k] = expf(ev[k] - mx); se += sc[k]; }
  float inv = 1.f / se;
  float clu = 0.f;
  #pragma unroll
  for (int k = 0; k < Kk; ++k) clu += sc[k] * inv * hs[k][tid];

  float r1 = bred(clu * w1w[tid]);
  float r2 = bred(ht * w2w[tid]);
  float a1 = sigm(r1 + w1b[0]);
  float a2 = sigm(r2 + w2b[0]);
  float wn = a1 / (a1 + a2);
  out[(size_t)n * Hh + tid] = wn * clu + (1.f - wn) * ht;
}

// ---------------------------------------------------------------------------
// Host-side threefry2x32 (JAX), reproducing jax.random.permutation(key(42), 2048)[:12].
static void tf2x32(uint32_t k0, uint32_t k1, uint32_t c0, uint32_t c1,
                   uint32_t& o0, uint32_t& o1) {
  uint32_t ks2 = k0 ^ k1 ^ 0x1BD11BDAu;
  uint32_t x0 = c0 + k0, x1 = c1 + k1;
#define TFR(r) do { x0 += x1; x1 = (x1 << (r)) | (x1 >> (32 - (r))); x1 ^= x0; } while (0)
  TFR(13); TFR(15); TFR(26); TFR(6);
  x0 += k1;  x1 += ks2 + 1u;
  TFR(17); TFR(29); TFR(16); TFR(24);
  x0 += ks2; x1 += k0 + 2u;
  TFR(13); TFR(15); TFR(26); TFR(6);
  x0 += k0;  x1 += k1 + 3u;
  TFR(17); TFR(29); TFR(16); TFR(24);
  x0 += k1;  x1 += ks2 + 4u;
  TFR(13); TFR(15); TFR(26); TFR(6);
  x0 += ks2; x1 += k0 + 5u;
#undef TFR
  o0 = x0; o1 = x1;
}

static void compute_idx(int* out12) {
  uint32_t kh = 0u, kl = 42u;     // jax.random.key(42) -> (0, 42)
  std::vector<int> perm(Nn);
  for (int i = 0; i < Nn; ++i) perm[i] = i;
  std::vector<uint32_t> bits(Nn);
  std::vector<int> pos(Nn);
  for (int round = 0; round < 2; ++round) {     // 2 rounds for n=2048
    uint32_t nh, nl, sh, sl;
    tf2x32(kh, kl, 0u, 0u, nh, nl);             // split: counters (0,0),(0,1)
    tf2x32(kh, kl, 0u, 1u, sh, sl);
    kh = nh; kl = nl;
    // partitionable random_bits(32): bits[i] = o0 ^ o1 at counter (0, i)
    for (uint32_t i = 0; i < (uint32_t)Nn; ++i) {
      uint32_t o0, o1; tf2x32(sh, sl, 0u, i, o0, o1); bits[i] = o0 ^ o1;
    }
    for (int i = 0; i < Nn; ++i) pos[i] = i;
    std::stable_sort(pos.begin(), pos.end(),
                     [&](int a, int b) { return bits[a] < bits[b]; });
    std::vector<int> np(Nn);
    for (int i = 0; i < Nn; ++i) np[i] = perm[pos[i]];
    perm.swap(np);
  }
  for (int k = 0; k < Kk; ++k) out12[k] = perm[k];
}

// ---------------------------------------------------------------------------
extern "C" void kernel_launch(void* const* d_in, const int* in_sizes, int n_in,
                              void* d_out, int out_size, void* d_ws, size_t ws_size,
                              hipStream_t stream) {
  const float* x   = (const float*)d_in[0];
  const int*   len = (const int*)d_in[1];
  const float* Wih = (const float*)d_in[2];
  const float* Whh = (const float*)d_in[3];
  const float* bih = (const float*)d_in[4];
  const float* bhh = (const float*)d_in[5];
  const float* w1w = (const float*)d_in[6];
  const float* w1b = (const float*)d_in[7];
  const float* w2w = (const float*)d_in[8];
  const float* w2b = (const float*)d_in[9];
  const float* g1w = (const float*)d_in[10];
  const float* g1b = (const float*)d_in[11];
  const float* g2w = (const float*)d_in[12];
  const float* g2b = (const float*)d_in[13];
  float* out = (float*)d_out;

  float* wsf  = (float*)d_ws;
  float* hfin = wsf;                          // N*H
  float* cent = hfin + (size_t)Nn * Hh;       // K*H
  float* h2g  = cent + Kk * Hh;               // K*H
  float* part = h2g + Kk * Hh;                // 64*K*H
  int*   pcnt = (int*)(part + 64 * Kk * Hh);  // 64*K ints (pad to 1024)
  int*   gflag = pcnt + 768;                  // 2 ints
  float* pkw  = (float*)(pcnt + 1024);        // 393216 floats, 16B-aligned

  IdxArgs ia;
  compute_idx(ia.v);                          // host, deterministic, capture-safe

  pack_w<<<768, 64, 0, stream>>>(Wih, Whh, pkw);
  gru_q<<<256, 512, 0, stream>>>(x, len, pkw, bih, bhh, hfin);

  {
    void* ka[] = {(void*)&hfin, (void*)&cent, (void*)&part, (void*)&pcnt,
                  (void*)&gflag, (void*)&ia};
    hipLaunchCooperativeKernel((const void*)km_coop, dim3(64), dim3(256),
                               ka, 0, stream);
  }

  gcn<<<1, 256, 0, stream>>>(cent, g1w, g1b, g2w, g2b, h2g);
  finalk<<<Nn, 256, 0, stream>>>(hfin, cent, h2g, w1w, w1b, w2w, w2b, out);
}

// Round 11
// 5184.908 us; speedup vs baseline: 3.9072x; 1.0736x over previous
//
#include <hip/hip_runtime.h>
#include <hip/hip_cooperative_groups.h>
#include <cstdint>
#include <cstring>
#include <vector>
#include <algorithm>

namespace cg = cooperative_groups;

// ---------------------------------------------------------------------------
// GRASPLayer round 11: column-pair packed FMA (v_pk_fma_f32) in the GRU.
//  - W repacked interleaved {c,c+128} per k -> each thread's two columns are
//    the two lanes of a float2 ext-vector accumulator. Per-column summation
//    order identical to round-10 PASS (k-ascending, x,y,z,w) -> hfin bits
//    preserved (modulo fma contraction, now pinned explicitly).
//  - FMA issue halves: 6144 scalar -> 3072 v_pk_fma_f32 per thread per step.
//  - kmeans/gcn/finalk verbatim from round-10 PASS.
// ---------------------------------------------------------------------------

namespace {
constexpr int Nn = 2048;
constexpr int Tt = 128;
constexpr int Dd = 256;
constexpr int Hh = 256;
constexpr int Kk = 12;
constexpr int MAXIT = 100;
}

struct IdxArgs { int v[Kk]; };

typedef float v2f __attribute__((ext_vector_type(2)));

__device__ __forceinline__ float sigm(float x) { return 1.0f / (1.0f + expf(-x)); }

#if __has_builtin(__builtin_elementwise_fma)
#define PKFMA(A, X, W) (A) = __builtin_elementwise_fma((X), (W), (A))
#else
#define PKFMA(A, X, W) do { (A).x = __builtin_fmaf((X).x, (W).x, (A).x); \
                            (A).y = __builtin_fmaf((X).y, (W).y, (A).y); } while (0)
#endif
#define LO2(V) ((v2f){(V).x, (V).y})
#define HI2(V) ((v2f){(V).z, (V).w})

// ---------------------------------------------------------------------------
// Pack Wih/Whh [3*256 x 256] into pk[k4][g6][cp(128)][8], entry layout
// {c,k0},{c+128,k0},{c,k1},{c+128,k1},... so one float4 = 2 cols x 2 k.
__global__ __launch_bounds__(64) void pack_w(
    const float* __restrict__ Wih, const float* __restrict__ Whh,
    float* __restrict__ pk)
{
  const int j = blockIdx.x;            // 0..767 = w-row (g*256 + c)
  const int k4 = threadIdx.x;          // 0..63
  const int g = j >> 8, c = j & 255;
  const int cp = c & 127, sel = c >> 7;
  float4 vih = *(const float4*)&Wih[(size_t)j * 256 + k4 * 4];
  float4 vhh = *(const float4*)&Whh[(size_t)j * 256 + k4 * 4];
  float* dih = pk + (((size_t)k4 * 6 + g) * 128 + cp) * 8 + sel;
  float* dhh = pk + (((size_t)k4 * 6 + 3 + g) * 128 + cp) * 8 + sel;
  dih[0] = vih.x; dih[2] = vih.y; dih[4] = vih.z; dih[6] = vih.w;
  dhh[0] = vhh.x; dhh[2] = vhh.y; dhh[4] = vhh.z; dhh[6] = vhh.w;
}

// ---------------------------------------------------------------------------
// 256 blocks x 512 threads; block owns 8 rows. Thread (cp, q) accumulates
// cols {cp, cp+128} over k-quarter q with packed FMA. LDS tree combine;
// q==0 applies gates. Structure identical to round-10 PASS.
__global__ __launch_bounds__(512, 1) void gru_q(
    const float* __restrict__ x, const int* __restrict__ len,
    const float* __restrict__ pk,
    const float* __restrict__ bih, const float* __restrict__ bhh,
    float* __restrict__ hfin)
{
  __shared__ alignas(16) float xls[8][260];
  __shared__ alignas(16) float hls[8][260];
  __shared__ float4 pbuf[2][8][256];            // 64 KB combine buffer
  const int tid = threadIdx.x;
  const int cp = tid & 127;                     // columns cp, cp+128
  const int q  = tid >> 7;                      // k-quarter
  const int n0 = blockIdx.x * 8;
  const int C0 = cp, C1 = cp + 128;

  const float bir0 = bih[C0], bhr0 = bhh[C0];
  const float biz0 = bih[Hh + C0], bhz0 = bhh[Hh + C0];
  const float bin0 = bih[2 * Hh + C0], bhn0 = bhh[2 * Hh + C0];
  const float bir1 = bih[C1], bhr1 = bhh[C1];
  const float biz1 = bih[Hh + C1], bhz1 = bhh[Hh + C1];
  const float bin1 = bih[2 * Hh + C1], bhn1 = bhh[2 * Hh + C1];
  int L[8];
  #pragma unroll
  for (int r = 0; r < 8; ++r) L[r] = len[n0 + r];

  const int q16 = q * 16;
  const size_t cp8 = (size_t)cp * 8;

  if (tid < 256) {
    #pragma unroll
    for (int r = 0; r < 8; ++r) hls[r][tid] = 0.f;
  }

  for (int t = 0; t < Tt; ++t) {
    // stage x_t (512 float4, coalesced)
    {
      int row = tid >> 6, c4 = tid & 63;
      *(float4*)&xls[row][c4 * 4] =
          *(const float4*)&x[(size_t)(n0 + row) * (Tt * Dd) + (size_t)t * Dd + c4 * 4];
    }
    __syncthreads();   // orders x stage + hls updates + pbuf reuse

    v2f aR[8] = {}, aZ[8] = {}, aXN[8] = {}, aHN[8] = {};

    // ---- phase A: gx partials over k-quarter (k ascending) ----
    #pragma unroll 1
    for (int i = 0; i < 16; ++i) {
      const int k4 = q16 + i;
      const float* pb = pk + (size_t)k4 * 6144 + cp8;
      float4 rA = *(const float4*)(pb);
      float4 rB = *(const float4*)(pb + 4);
      float4 zA = *(const float4*)(pb + 1024);
      float4 zB = *(const float4*)(pb + 1028);
      float4 nA = *(const float4*)(pb + 2048);
      float4 nB = *(const float4*)(pb + 2052);
      const int k = k4 * 4;
      #pragma unroll
      for (int r = 0; r < 8; ++r) {
        float4 xv = *(const float4*)&xls[r][k];   // broadcast
        v2f s0 = {xv.x, xv.x}, s1 = {xv.y, xv.y};
        v2f s2 = {xv.z, xv.z}, s3 = {xv.w, xv.w};
        PKFMA(aR[r],  s0, LO2(rA)); PKFMA(aR[r],  s1, HI2(rA));
        PKFMA(aR[r],  s2, LO2(rB)); PKFMA(aR[r],  s3, HI2(rB));
        PKFMA(aZ[r],  s0, LO2(zA)); PKFMA(aZ[r],  s1, HI2(zA));
        PKFMA(aZ[r],  s2, LO2(zB)); PKFMA(aZ[r],  s3, HI2(zB));
        PKFMA(aXN[r], s0, LO2(nA)); PKFMA(aXN[r], s1, HI2(nA));
        PKFMA(aXN[r], s2, LO2(nB)); PKFMA(aXN[r], s3, HI2(nB));
      }
    }
    // ---- phase B: gh partials over k-quarter ----
    #pragma unroll 1
    for (int i = 0; i < 16; ++i) {
      const int k4 = q16 + i;
      const float* pb = pk + (size_t)k4 * 6144 + 3072 + cp8;
      float4 rA = *(const float4*)(pb);
      float4 rB = *(const float4*)(pb + 4);
      float4 zA = *(const float4*)(pb + 1024);
      float4 zB = *(const float4*)(pb + 1028);
      float4 nA = *(const float4*)(pb + 2048);
      float4 nB = *(const float4*)(pb + 2052);
      const int k = k4 * 4;
      #pragma unroll
      for (int r = 0; r < 8; ++r) {
        float4 hv = *(const float4*)&hls[r][k];   // broadcast
        v2f s0 = {hv.x, hv.x}, s1 = {hv.y, hv.y};
        v2f s2 = {hv.z, hv.z}, s3 = {hv.w, hv.w};
        PKFMA(aR[r],  s0, LO2(rA)); PKFMA(aR[r],  s1, HI2(rA));
        PKFMA(aR[r],  s2, LO2(rB)); PKFMA(aR[r],  s3, HI2(rB));
        PKFMA(aZ[r],  s0, LO2(zA)); PKFMA(aZ[r],  s1, HI2(zA));
        PKFMA(aZ[r],  s2, LO2(zB)); PKFMA(aZ[r],  s3, HI2(zB));
        PKFMA(aHN[r], s0, LO2(nA)); PKFMA(aHN[r], s1, HI2(nA));
        PKFMA(aHN[r], s2, LO2(nB)); PKFMA(aHN[r], s3, HI2(nB));
      }
    }

    // ---- combine tree: (q0+=q1, q2+=q3) then q0 += q2' ----
    if (q == 1 || q == 3) {
      const int reg = q >> 1;
      #pragma unroll
      for (int r = 0; r < 8; ++r) {
        pbuf[reg][r][C0] = make_float4(aR[r].x, aZ[r].x, aXN[r].x, aHN[r].x);
        pbuf[reg][r][C1] = make_float4(aR[r].y, aZ[r].y, aXN[r].y, aHN[r].y);
      }
    }
    __syncthreads();
    if (q == 0 || q == 2) {
      const int reg = q >> 1;
      #pragma unroll
      for (int r = 0; r < 8; ++r) {
        float4 p0 = pbuf[reg][r][C0];
        float4 p1 = pbuf[reg][r][C1];
        aR[r].x += p0.x; aZ[r].x += p0.y; aXN[r].x += p0.z; aHN[r].x += p0.w;
        aR[r].y += p1.x; aZ[r].y += p1.y; aXN[r].y += p1.z; aHN[r].y += p1.w;
      }
    }
    __syncthreads();
    if (q == 2) {
      #pragma unroll
      for (int r = 0; r < 8; ++r) {
        pbuf[0][r][C0] = make_float4(aR[r].x, aZ[r].x, aXN[r].x, aHN[r].x);
        pbuf[0][r][C1] = make_float4(aR[r].y, aZ[r].y, aXN[r].y, aHN[r].y);
      }
    }
    __syncthreads();

    // ---- gates (q==0 threads; order r,z,n, PyTorch layout) ----
    if (q == 0) {
      #pragma unroll
      for (int r = 0; r < 8; ++r) {
        if (t < L[r]) {
          float4 p0 = pbuf[0][r][C0];
          float4 p1 = pbuf[0][r][C1];
          float sR0 = aR[r].x + p0.x, sZ0 = aZ[r].x + p0.y;
          float sX0 = aXN[r].x + p0.z, sH0 = aHN[r].x + p0.w;
          float sR1 = aR[r].y + p1.x, sZ1 = aZ[r].y + p1.y;
          float sX1 = aXN[r].y + p1.z, sH1 = aHN[r].y + p1.w;
          float rg0 = sigm(sR0 + bir0 + bhr0);
          float zg0 = sigm(sZ0 + biz0 + bhz0);
          float ng0 = tanhf(sX0 + bin0 + rg0 * (sH0 + bhn0));
          float hv0 = (1.f - zg0) * ng0 + zg0 * hls[r][C0];
          float rg1 = sigm(sR1 + bir1 + bhr1);
          float zg1 = sigm(sZ1 + biz1 + bhz1);
          float ng1 = tanhf(sX1 + bin1 + rg1 * (sH1 + bhn1));
          float hv1 = (1.f - zg1) * ng1 + zg1 * hls[r][C1];
          hls[r][C0] = hv0;
          hls[r][C1] = hv1;
          if (t == L[r] - 1) {
            hfin[(size_t)(n0 + r) * Hh + C0] = hv0;
            hfin[(size_t)(n0 + r) * Hh + C1] = hv1;
          }
        }
      }
    }
    // next iteration's top __syncthreads orders hls/pbuf reuse
  }
}

// ---------------------------------------------------------------------------
// Cooperative kmeans (verbatim round-10 PASS): 64 blocks x 256 threads,
// 32 rows/block (wave owns 8); fixed-point early exit.
__global__ __launch_bounds__(256, 1) void km_coop(
    const float* __restrict__ hfin, float* __restrict__ cent,
    float* __restrict__ part, int* __restrict__ pcnt,
    int* __restrict__ gflag, IdxArgs ia)
{
  __shared__ alignas(16) float rows_l[32][260];
  __shared__ alignas(16) float cs[Kk][260];
  __shared__ float psl[Kk][256];
  __shared__ float c2s[Kk];
  __shared__ int codes_l[32];
  __shared__ int pcl[Kk];
  __shared__ int chg_l, brk_l;
  cg::grid_group grid = cg::this_grid();
  const int tid = threadIdx.x, lane = tid & 63, w = tid >> 6;
  const int blk = blockIdx.x, n0 = blk * 32;

  #pragma unroll
  for (int i = 0; i < 8; ++i) {
    int f = tid + i * 256;
    int row = f >> 6, c4 = f & 63;
    *(float4*)&rows_l[row][c4 * 4] =
        *(const float4*)&hfin[(size_t)(n0 + row) * Hh + c4 * 4];
  }
  if (tid < 32) codes_l[tid] = -1;
  if (blk == 0) {
    if (tid == 0) { gflag[0] = 0; gflag[1] = 0; }
    #pragma unroll
    for (int i = 0; i < 3; ++i) {
      int f = tid + i * 256;
      int k = f >> 6, c4 = f & 63;
      *(float4*)&cent[(size_t)k * Hh + c4 * 4] =
          *(const float4*)&hfin[(size_t)ia.v[k] * Hh + c4 * 4];
    }
  }
  __syncthreads();
  float4 v4[8];
  #pragma unroll
  for (int rr = 0; rr < 8; ++rr)
    v4[rr] = *(const float4*)&rows_l[w * 8 + rr][lane * 4];
  __threadfence();
  grid.sync();

  for (int it = 0; it < MAXIT; ++it) {
    #pragma unroll
    for (int i = 0; i < 3; ++i) {
      int f = tid + i * 256;
      int k = f >> 6, c4 = f & 63;
      float4 cv = (it == 0)
          ? *(const float4*)&hfin[(size_t)ia.v[k] * Hh + c4 * 4]
          : *(const float4*)&cent[(size_t)k * Hh + c4 * 4];
      *(float4*)&cs[k][c4 * 4] = cv;
    }
    if (tid == 0) chg_l = 0;
    if (tid < Kk) pcl[tid] = 0;
    __syncthreads();
    if (tid < Kk) {
      float s = 0.f;
      for (int c = 0; c < Hh; ++c) { float v = cs[tid][c]; s += v * v; }
      c2s[tid] = s;
    }
    __syncthreads();

    int mych = 0;
    #pragma unroll
    for (int rr = 0; rr < 8; ++rr) {
      const int row = w * 8 + rr;
      float best = 3.4e38f; int bi = 0;
      #pragma unroll
      for (int k = 0; k < Kk; ++k) {
        float4 cv = *(const float4*)&cs[k][lane * 4];
        float p = v4[rr].x * cv.x + v4[rr].y * cv.y
                + v4[rr].z * cv.z + v4[rr].w * cv.w;
        #pragma unroll
        for (int m = 1; m < 64; m <<= 1) p += __shfl_xor(p, m, 64);
        float d = c2s[k] - 2.f * p;
        if (d < best) { best = d; bi = k; }
      }
      if (lane == 0) {
        if (bi != codes_l[row]) mych = 1;
        codes_l[row] = bi;
      }
    }
    if (mych) atomicOr(&chg_l, 1);
    __syncthreads();

    #pragma unroll
    for (int k = 0; k < Kk; ++k) psl[k][tid] = 0.f;
    for (int r = 0; r < 32; ++r)
      psl[codes_l[r]][tid] += rows_l[r][tid];
    if (tid < 32) atomicAdd(&pcl[codes_l[tid]], 1);
    if (tid == 0 && chg_l) atomicOr(&gflag[it & 1], 1);
    __syncthreads();
    #pragma unroll
    for (int k = 0; k < Kk; ++k)
      part[((size_t)blk * Kk + k) * Hh + tid] = psl[k][tid];
    if (tid < Kk) pcnt[blk * Kk + tid] = pcl[tid];
    __threadfence();
    grid.sync();

    if (blk < Kk) {
      float s = 0.f;
      for (int p = 0; p < 64; ++p) s += part[((size_t)p * Kk + blk) * Hh + tid];
      int cn = 0;
      for (int p = 0; p < 64; ++p) cn += pcnt[p * Kk + blk];
      if (cn > 0) cent[(size_t)blk * Hh + tid] = s / (float)cn;
    }
    if (blk == 0 && tid == 0) gflag[(it + 1) & 1] = 0;
    __threadfence();
    grid.sync();
    if (tid == 0) brk_l = atomicAdd(&gflag[it & 1], 0);
    __syncthreads();
    if (brk_l == 0) break;
  }
}

// ---------------------------------------------------------------------------
// h1 = relu(centers@g1_w + g1_b); h2 = relu(h1@g2_w + g2_b). One block.
__global__ __launch_bounds__(256) void gcn(
    const float* __restrict__ cent, const float* __restrict__ g1w,
    const float* __restrict__ g1b, const float* __restrict__ g2w,
    const float* __restrict__ g2b, float* __restrict__ h2out)
{
  __shared__ float a[Kk][Hh];
  __shared__ float b[Kk][Hh];
  int c = threadIdx.x;
  for (int i = c; i < Kk * Hh; i += 256) ((float*)a)[i] = cent[i];
  __syncthreads();
  float acc[Kk];
  #pragma unroll
  for (int k = 0; k < Kk; ++k) acc[k] = 0.f;
  for (int j = 0; j < Hh; ++j) {
    float wv = g1w[(size_t)j * Hh + c];
    #pragma unroll
    for (int k = 0; k < Kk; ++k) acc[k] += a[k][j] * wv;
  }
  #pragma unroll
  for (int k = 0; k < Kk; ++k) b[k][c] = fmaxf(acc[k] + g1b[c], 0.f);
  __syncthreads();
  #pragma unroll
  for (int k = 0; k < Kk; ++k) acc[k] = 0.f;
  for (int j = 0; j < Hh; ++j) {
    float wv = g2w[(size_t)j * Hh + c];
    #pragma unroll
    for (int k = 0; k < Kk; ++k) acc[k] += b[k][j] * wv;
  }
  #pragma unroll
  for (int k = 0; k < Kk; ++k) h2out[k * Hh + c] = fmaxf(acc[k] + g2b[c], 0.f);
}

// scores = softmax(relu(ht@centers^T)); clu = scores@h2; gated blend. 1 block/row.
__global__ __launch_bounds__(256) void finalk(
    const float* __restrict__ hfin, const float* __restrict__ cent,
    const float* __restrict__ h2, const float* __restrict__ w1w,
    const float* __restrict__ w1b, const float* __restrict__ w2w,
    const float* __restrict__ w2b, float* __restrict__ out)
{
  __shared__ alignas(16) float cs[Kk][Hh];
  __shared__ alignas(16) float hs[Kk][Hh];
  __shared__ float red[4];
  const int tid = threadIdx.x, lane = tid & 63, w = tid >> 6;
  const int n = blockIdx.x;
  for (int i = tid; i < Kk * Hh; i += 256) { ((float*)cs)[i] = cent[i]; ((float*)hs)[i] = h2[i]; }
  float ht = hfin[(size_t)n * Hh + tid];
  __syncthreads();

  auto bred = [&](float v) -> float {
    #pragma unroll
    for (int m = 1; m < 64; m <<= 1) v += __shfl_xor(v, m, 64);
    __syncthreads();
    if (lane == 0) red[w] = v;
    __syncthreads();
    return red[0] + red[1] + red[2] + red[3];
  };

  float ev[Kk];
  #pragma unroll
  for (int k = 0; k < Kk; ++k)
    ev[k] = fmaxf(bred(ht * cs[k][tid]), 0.f);

  float mx = ev[0];
  #pragma unroll
  for (int k = 1; k < Kk; ++k) mx = fmaxf(mx, ev[k]);
  float se = 0.f; float sc[Kk];
  #pragma unroll
  for (int k = 0; k < Kk; ++k) { sc[k] = expf(ev[k] - mx); se += sc[k]; }
  float inv = 1.f / se;
  float clu = 0.f;
  #pragma unroll
  for (int k = 0; k < Kk; ++k) clu += sc[k] * inv * hs[k][tid];

  float r1 = bred(clu * w1w[tid]);
  float r2 = bred(ht * w2w[tid]);
  float a1 = sigm(r1 + w1b[0]);
  float a2 = sigm(r2 + w2b[0]);
  float wn = a1 / (a1 + a2);
  out[(size_t)n * Hh + tid] = wn * clu + (1.f - wn) * ht;
}

// ---------------------------------------------------------------------------
// Host-side threefry2x32 (JAX), reproducing jax.random.permutation(key(42), 2048)[:12].
static void tf2x32(uint32_t k0, uint32_t k1, uint32_t c0, uint32_t c1,
                   uint32_t& o0, uint32_t& o1) {
  uint32_t ks2 = k0 ^ k1 ^ 0x1BD11BDAu;
  uint32_t x0 = c0 + k0, x1 = c1 + k1;
#define TFR(r) do { x0 += x1; x1 = (x1 << (r)) | (x1 >> (32 - (r))); x1 ^= x0; } while (0)
  TFR(13); TFR(15); TFR(26); TFR(6);
  x0 += k1;  x1 += ks2 + 1u;
  TFR(17); TFR(29); TFR(16); TFR(24);
  x0 += ks2; x1 += k0 + 2u;
  TFR(13); TFR(15); TFR(26); TFR(6);
  x0 += k0;  x1 += k1 + 3u;
  TFR(17); TFR(29); TFR(16); TFR(24);
  x0 += k1;  x1 += ks2 + 4u;
  TFR(13); TFR(15); TFR(26); TFR(6);
  x0 += ks2; x1 += k0 + 5u;
#undef TFR
  o0 = x0; o1 = x1;
}

static void compute_idx(int* out12) {
  uint32_t kh = 0u, kl = 42u;     // jax.random.key(42) -> (0, 42)
  std::vector<int> perm(Nn);
  for (int i = 0; i < Nn; ++i) perm[i] = i;
  std::vector<uint32_t> bits(Nn);
  std::vector<int> pos(Nn);
  for (int round = 0; round < 2; ++round) {     // 2 rounds for n=2048
    uint32_t nh, nl, sh, sl;
    tf2x32(kh, kl, 0u, 0u, nh, nl);             // split: counters (0,0),(0,1)
    tf2x32(kh, kl, 0u, 1u, sh, sl);
    kh = nh; kl = nl;
    // partitionable random_bits(32): bits[i] = o0 ^ o1 at counter (0, i)
    for (uint32_t i = 0; i < (uint32_t)Nn; ++i) {
      uint32_t o0, o1; tf2x32(sh, sl, 0u, i, o0, o1); bits[i] = o0 ^ o1;
    }
    for (int i = 0; i < Nn; ++i) pos[i] = i;
    std::stable_sort(pos.begin(), pos.end(),
                     [&](int a, int b) { return bits[a] < bits[b]; });
    std::vector<int> np(Nn);
    for (int i = 0; i < Nn; ++i) np[i] = perm[pos[i]];
    perm.swap(np);
  }
  for (int k = 0; k < Kk; ++k) out12[k] = perm[k];
}

// ---------------------------------------------------------------------------
extern "C" void kernel_launch(void* const* d_in, const int* in_sizes, int n_in,
                              void* d_out, int out_size, void* d_ws, size_t ws_size,
                              hipStream_t stream) {
  const float* x   = (const float*)d_in[0];
  const int*   len = (const int*)d_in[1];
  const float* Wih = (const float*)d_in[2];
  const float* Whh = (const float*)d_in[3];
  const float* bih = (const float*)d_in[4];
  const float* bhh = (const float*)d_in[5];
  const float* w1w = (const float*)d_in[6];
  const float* w1b = (const float*)d_in[7];
  const float* w2w = (const float*)d_in[8];
  const float* w2b = (const float*)d_in[9];
  const float* g1w = (const float*)d_in[10];
  const float* g1b = (const float*)d_in[11];
  const float* g2w = (const float*)d_in[12];
  const float* g2b = (const float*)d_in[13];
  float* out = (float*)d_out;

  float* wsf  = (float*)d_ws;
  float* hfin = wsf;                          // N*H
  float* cent = hfin + (size_t)Nn * Hh;       // K*H
  float* h2g  = cent + Kk * Hh;               // K*H
  float* part = h2g + Kk * Hh;                // 64*K*H
  int*   pcnt = (int*)(part + 64 * Kk * Hh);  // 64*K ints (pad to 1024)
  int*   gflag = pcnt + 768;                  // 2 ints
  float* pkw  = (float*)(pcnt + 1024);        // 393216 floats, 16B-aligned

  IdxArgs ia;
  compute_idx(ia.v);                          // host, deterministic, capture-safe

  pack_w<<<768, 64, 0, stream>>>(Wih, Whh, pkw);
  gru_q<<<256, 512, 0, stream>>>(x, len, pkw, bih, bhh, hfin);

  {
    void* ka[] = {(void*)&hfin, (void*)&cent, (void*)&part, (void*)&pcnt,
                  (void*)&gflag, (void*)&ia};
    hipLaunchCooperativeKernel((const void*)km_coop, dim3(64), dim3(256),
                               ka, 0, stream);
  }

  gcn<<<1, 256, 0, stream>>>(cent, g1w, g1b, g2w, g2b, h2g);
  finalk<<<Nn, 256, 0, stream>>>(hfin, cent, h2g, w1w, w1b, w2w, w2b, out);
}

// Round 12
// 5088.005 us; speedup vs baseline: 3.9817x; 1.0190x over previous
//
#include <hip/hip_runtime.h>
#include <hip/hip_cooperative_groups.h>
#include <cstdint>
#include <cstring>
#include <vector>
#include <algorithm>

namespace cg = cooperative_groups;

// ---------------------------------------------------------------------------
// GRASPLayer round 12: k-pair packed FMA, zero marshalling.
//  - W in r10 natural layout (float4 = 4 adjacent k per column). Packed FMA
//    pairs adjacent k: acc2 += {x[k],x[k+1]}*{W[c][k],W[c][k+1]} — both
//    operands are free sub-register pairs of loaded float4s (no splats).
//  - v2f accumulators (even-k, odd-k lanes) folded once per step before the
//    r10 combine tree. Summation-order change is 1e-7-level (r8 precedent).
//  - kmeans/gcn/finalk verbatim from round-10/11 PASS.
// ---------------------------------------------------------------------------

namespace {
constexpr int Nn = 2048;
constexpr int Tt = 128;
constexpr int Dd = 256;
constexpr int Hh = 256;
constexpr int Kk = 12;
constexpr int MAXIT = 100;
}

struct IdxArgs { int v[Kk]; };

typedef float v2f __attribute__((ext_vector_type(2)));

__device__ __forceinline__ float sigm(float x) { return 1.0f / (1.0f + expf(-x)); }

#if __has_builtin(__builtin_elementwise_fma)
#define PKFMA(A, X, W) (A) = __builtin_elementwise_fma((X), (W), (A))
#else
#define PKFMA(A, X, W) do { (A).x = __builtin_fmaf((X).x, (W).x, (A).x); \
                            (A).y = __builtin_fmaf((X).y, (W).y, (A).y); } while (0)
#endif
#define LO2(V) ((v2f){(V).x, (V).y})
#define HI2(V) ((v2f){(V).z, (V).w})

// ---------------------------------------------------------------------------
// Pack Wih/Whh [3*256 x 256] into pk[k4][g][c][4] (r10 layout: float4 = 4
// adjacent k of column c), g in {ihr,ihz,ihn,hhr,hhz,hhn}.
__global__ __launch_bounds__(64) void pack_w(
    const float* __restrict__ Wih, const float* __restrict__ Whh,
    float* __restrict__ pk)
{
  const int j = blockIdx.x;            // 0..767 = w-row (g*256 + c)
  const int k4 = threadIdx.x;          // 0..63
  const int g = j >> 8, c = j & 255;
  float4 vih = *(const float4*)&Wih[(size_t)j * 256 + k4 * 4];
  float4 vhh = *(const float4*)&Whh[(size_t)j * 256 + k4 * 4];
  *(float4*)&pk[(((size_t)k4 * 6 + g) * 256 + c) * 4]       = vih;
  *(float4*)&pk[(((size_t)k4 * 6 + 3 + g) * 256 + c) * 4]   = vhh;
}

// ---------------------------------------------------------------------------
// 256 blocks x 512 threads; block owns 8 rows. Thread (cp, q) accumulates
// cols {cp, cp+128} over k-quarter q with k-pair packed FMA. LDS tree
// combine; q==0 applies gates. Structure identical to round-10 PASS.
__global__ __launch_bounds__(512, 1) void gru_q(
    const float* __restrict__ x, const int* __restrict__ len,
    const float* __restrict__ pk,
    const float* __restrict__ bih, const float* __restrict__ bhh,
    float* __restrict__ hfin)
{
  __shared__ alignas(16) float xls[8][260];
  __shared__ alignas(16) float hls[8][260];
  __shared__ float4 pbuf[2][8][256];            // 64 KB combine buffer
  const int tid = threadIdx.x;
  const int cp = tid & 127;                     // columns cp, cp+128
  const int q  = tid >> 7;                      // k-quarter
  const int n0 = blockIdx.x * 8;
  const int C0 = cp, C1 = cp + 128;

  const float bir0 = bih[C0], bhr0 = bhh[C0];
  const float biz0 = bih[Hh + C0], bhz0 = bhh[Hh + C0];
  const float bin0 = bih[2 * Hh + C0], bhn0 = bhh[2 * Hh + C0];
  const float bir1 = bih[C1], bhr1 = bhh[C1];
  const float biz1 = bih[Hh + C1], bhz1 = bhh[Hh + C1];
  const float bin1 = bih[2 * Hh + C1], bhn1 = bhh[2 * Hh + C1];
  int L[8];
  #pragma unroll
  for (int r = 0; r < 8; ++r) L[r] = len[n0 + r];

  const int q16 = q * 16;
  const size_t cp4 = (size_t)cp * 4;

  if (tid < 256) {
    #pragma unroll
    for (int r = 0; r < 8; ++r) hls[r][tid] = 0.f;
  }

  for (int t = 0; t < Tt; ++t) {
    // stage x_t (512 float4, coalesced)
    {
      int row = tid >> 6, c4 = tid & 63;
      *(float4*)&xls[row][c4 * 4] =
          *(const float4*)&x[(size_t)(n0 + row) * (Tt * Dd) + (size_t)t * Dd + c4 * 4];
    }
    __syncthreads();   // orders x stage + hls updates + pbuf reuse

    // v2f accumulators: .x = even-k chain, .y = odd-k chain
    v2f aR[8][2] = {}, aZ[8][2] = {}, aXN[8][2] = {}, aHN[8][2] = {};

    // ---- phase A: gx partials over k-quarter (k ascending) ----
    #pragma unroll 1
    for (int i = 0; i < 16; ++i) {
      const int k4 = q16 + i;
      const float* pb = pk + (size_t)k4 * 6144 + cp4;
      float4 wr0 = *(const float4*)(pb);
      float4 wr1 = *(const float4*)(pb + 512);
      float4 wz0 = *(const float4*)(pb + 1024);
      float4 wz1 = *(const float4*)(pb + 1536);
      float4 wn0 = *(const float4*)(pb + 2048);
      float4 wn1 = *(const float4*)(pb + 2560);
      const int k = k4 * 4;
      #pragma unroll
      for (int r = 0; r < 8; ++r) {
        float4 xv = *(const float4*)&xls[r][k];   // broadcast
        v2f xlo = LO2(xv), xhi = HI2(xv);         // free sub-reg pairs
        PKFMA(aR[r][0],  xlo, LO2(wr0)); PKFMA(aR[r][0],  xhi, HI2(wr0));
        PKFMA(aR[r][1],  xlo, LO2(wr1)); PKFMA(aR[r][1],  xhi, HI2(wr1));
        PKFMA(aZ[r][0],  xlo, LO2(wz0)); PKFMA(aZ[r][0],  xhi, HI2(wz0));
        PKFMA(aZ[r][1],  xlo, LO2(wz1)); PKFMA(aZ[r][1],  xhi, HI2(wz1));
        PKFMA(aXN[r][0], xlo, LO2(wn0)); PKFMA(aXN[r][0], xhi, HI2(wn0));
        PKFMA(aXN[r][1], xlo, LO2(wn1)); PKFMA(aXN[r][1], xhi, HI2(wn1));
      }
    }
    // ---- phase B: gh partials over k-quarter ----
    #pragma unroll 1
    for (int i = 0; i < 16; ++i) {
      const int k4 = q16 + i;
      const float* pb = pk + (size_t)k4 * 6144 + 3072 + cp4;
      float4 wr0 = *(const float4*)(pb);
      float4 wr1 = *(const float4*)(pb + 512);
      float4 wz0 = *(const float4*)(pb + 1024);
      float4 wz1 = *(const float4*)(pb + 1536);
      float4 wn0 = *(const float4*)(pb + 2048);
      float4 wn1 = *(const float4*)(pb + 2560);
      const int k = k4 * 4;
      #pragma unroll
      for (int r = 0; r < 8; ++r) {
        float4 hv = *(const float4*)&hls[r][k];   // broadcast
        v2f hlo = LO2(hv), hhi = HI2(hv);
        PKFMA(aR[r][0],  hlo, LO2(wr0)); PKFMA(aR[r][0],  hhi, HI2(wr0));
        PKFMA(aR[r][1],  hlo, LO2(wr1)); PKFMA(aR[r][1],  hhi, HI2(wr1));
        PKFMA(aZ[r][0],  hlo, LO2(wz0)); PKFMA(aZ[r][0],  hhi, HI2(wz0));
        PKFMA(aZ[r][1],  hlo, LO2(wz1)); PKFMA(aZ[r][1],  hhi, HI2(wz1));
        PKFMA(aHN[r][0], hlo, LO2(wn0)); PKFMA(aHN[r][0], hhi, HI2(wn0));
        PKFMA(aHN[r][1], hlo, LO2(wn1)); PKFMA(aHN[r][1], hhi, HI2(wn1));
      }
    }

    // ---- fold even/odd-k lanes to scalars ----
    float fR[8][2], fZ[8][2], fX[8][2], fH[8][2];
    #pragma unroll
    for (int r = 0; r < 8; ++r) {
      fR[r][0] = aR[r][0].x + aR[r][0].y;  fR[r][1] = aR[r][1].x + aR[r][1].y;
      fZ[r][0] = aZ[r][0].x + aZ[r][0].y;  fZ[r][1] = aZ[r][1].x + aZ[r][1].y;
      fX[r][0] = aXN[r][0].x + aXN[r][0].y; fX[r][1] = aXN[r][1].x + aXN[r][1].y;
      fH[r][0] = aHN[r][0].x + aHN[r][0].y; fH[r][1] = aHN[r][1].x + aHN[r][1].y;
    }

    // ---- combine tree: (q0+=q1, q2+=q3) then q0 += q2' ----
    if (q == 1 || q == 3) {
      const int reg = q >> 1;
      #pragma unroll
      for (int r = 0; r < 8; ++r) {
        pbuf[reg][r][C0] = make_float4(fR[r][0], fZ[r][0], fX[r][0], fH[r][0]);
        pbuf[reg][r][C1] = make_float4(fR[r][1], fZ[r][1], fX[r][1], fH[r][1]);
      }
    }
    __syncthreads();
    if (q == 0 || q == 2) {
      const int reg = q >> 1;
      #pragma unroll
      for (int r = 0; r < 8; ++r) {
        float4 p0 = pbuf[reg][r][C0];
        float4 p1 = pbuf[reg][r][C1];
        fR[r][0] += p0.x; fZ[r][0] += p0.y; fX[r][0] += p0.z; fH[r][0] += p0.w;
        fR[r][1] += p1.x; fZ[r][1] += p1.y; fX[r][1] += p1.z; fH[r][1] += p1.w;
      }
    }
    __syncthreads();
    if (q == 2) {
      #pragma unroll
      for (int r = 0; r < 8; ++r) {
        pbuf[0][r][C0] = make_float4(fR[r][0], fZ[r][0], fX[r][0], fH[r][0]);
        pbuf[0][r][C1] = make_float4(fR[r][1], fZ[r][1], fX[r][1], fH[r][1]);
      }
    }
    __syncthreads();

    // ---- gates (q==0 threads; order r,z,n, PyTorch layout) ----
    if (q == 0) {
      #pragma unroll
      for (int r = 0; r < 8; ++r) {
        if (t < L[r]) {
          float4 p0 = pbuf[0][r][C0];
          float4 p1 = pbuf[0][r][C1];
          float sR0 = fR[r][0] + p0.x, sZ0 = fZ[r][0] + p0.y;
          float sX0 = fX[r][0] + p0.z, sH0 = fH[r][0] + p0.w;
          float sR1 = fR[r][1] + p1.x, sZ1 = fZ[r][1] + p1.y;
          float sX1 = fX[r][1] + p1.z, sH1 = fH[r][1] + p1.w;
          float rg0 = sigm(sR0 + bir0 + bhr0);
          float zg0 = sigm(sZ0 + biz0 + bhz0);
          float ng0 = tanhf(sX0 + bin0 + rg0 * (sH0 + bhn0));
          float hv0 = (1.f - zg0) * ng0 + zg0 * hls[r][C0];
          float rg1 = sigm(sR1 + bir1 + bhr1);
          float zg1 = sigm(sZ1 + biz1 + bhz1);
          float ng1 = tanhf(sX1 + bin1 + rg1 * (sH1 + bhn1));
          float hv1 = (1.f - zg1) * ng1 + zg1 * hls[r][C1];
          hls[r][C0] = hv0;
          hls[r][C1] = hv1;
          if (t == L[r] - 1) {
            hfin[(size_t)(n0 + r) * Hh + C0] = hv0;
            hfin[(size_t)(n0 + r) * Hh + C1] = hv1;
          }
        }
      }
    }
    // next iteration's top __syncthreads orders hls/pbuf reuse
  }
}

// ---------------------------------------------------------------------------
// Cooperative kmeans (verbatim round-10/11 PASS): 64 blocks x 256 threads,
// 32 rows/block (wave owns 8); fixed-point early exit.
__global__ __launch_bounds__(256, 1) void km_coop(
    const float* __restrict__ hfin, float* __restrict__ cent,
    float* __restrict__ part, int* __restrict__ pcnt,
    int* __restrict__ gflag, IdxArgs ia)
{
  __shared__ alignas(16) float rows_l[32][260];
  __shared__ alignas(16) float cs[Kk][260];
  __shared__ float psl[Kk][256];
  __shared__ float c2s[Kk];
  __shared__ int codes_l[32];
  __shared__ int pcl[Kk];
  __shared__ int chg_l, brk_l;
  cg::grid_group grid = cg::this_grid();
  const int tid = threadIdx.x, lane = tid & 63, w = tid >> 6;
  const int blk = blockIdx.x, n0 = blk * 32;

  #pragma unroll
  for (int i = 0; i < 8; ++i) {
    int f = tid + i * 256;
    int row = f >> 6, c4 = f & 63;
    *(float4*)&rows_l[row][c4 * 4] =
        *(const float4*)&hfin[(size_t)(n0 + row) * Hh + c4 * 4];
  }
  if (tid < 32) codes_l[tid] = -1;
  if (blk == 0) {
    if (tid == 0) { gflag[0] = 0; gflag[1] = 0; }
    #pragma unroll
    for (int i = 0; i < 3; ++i) {
      int f = tid + i * 256;
      int k = f >> 6, c4 = f & 63;
      *(float4*)&cent[(size_t)k * Hh + c4 * 4] =
          *(const float4*)&hfin[(size_t)ia.v[k] * Hh + c4 * 4];
    }
  }
  __syncthreads();
  float4 v4[8];
  #pragma unroll
  for (int rr = 0; rr < 8; ++rr)
    v4[rr] = *(const float4*)&rows_l[w * 8 + rr][lane * 4];
  __threadfence();
  grid.sync();

  for (int it = 0; it < MAXIT; ++it) {
    #pragma unroll
    for (int i = 0; i < 3; ++i) {
      int f = tid + i * 256;
      int k = f >> 6, c4 = f & 63;
      float4 cv = (it == 0)
          ? *(const float4*)&hfin[(size_t)ia.v[k] * Hh + c4 * 4]
          : *(const float4*)&cent[(size_t)k * Hh + c4 * 4];
      *(float4*)&cs[k][c4 * 4] = cv;
    }
    if (tid == 0) chg_l = 0;
    if (tid < Kk) pcl[tid] = 0;
    __syncthreads();
    if (tid < Kk) {
      float s = 0.f;
      for (int c = 0; c < Hh; ++c) { float v = cs[tid][c]; s += v * v; }
      c2s[tid] = s;
    }
    __syncthreads();

    int mych = 0;
    #pragma unroll
    for (int rr = 0; rr < 8; ++rr) {
      const int row = w * 8 + rr;
      float best = 3.4e38f; int bi = 0;
      #pragma unroll
      for (int k = 0; k < Kk; ++k) {
        float4 cv = *(const float4*)&cs[k][lane * 4];
        float p = v4[rr].x * cv.x + v4[rr].y * cv.y
                + v4[rr].z * cv.z + v4[rr].w * cv.w;
        #pragma unroll
        for (int m = 1; m < 64; m <<= 1) p += __shfl_xor(p, m, 64);
        float d = c2s[k] - 2.f * p;
        if (d < best) { best = d; bi = k; }
      }
      if (lane == 0) {
        if (bi != codes_l[row]) mych = 1;
        codes_l[row] = bi;
      }
    }
    if (mych) atomicOr(&chg_l, 1);
    __syncthreads();

    #pragma unroll
    for (int k = 0; k < Kk; ++k) psl[k][tid] = 0.f;
    for (int r = 0; r < 32; ++r)
      psl[codes_l[r]][tid] += rows_l[r][tid];
    if (tid < 32) atomicAdd(&pcl[codes_l[tid]], 1);
    if (tid == 0 && chg_l) atomicOr(&gflag[it & 1], 1);
    __syncthreads();
    #pragma unroll
    for (int k = 0; k < Kk; ++k)
      part[((size_t)blk * Kk + k) * Hh + tid] = psl[k][tid];
    if (tid < Kk) pcnt[blk * Kk + tid] = pcl[tid];
    __threadfence();
    grid.sync();

    if (blk < Kk) {
      float s = 0.f;
      for (int p = 0; p < 64; ++p) s += part[((size_t)p * Kk + blk) * Hh + tid];
      int cn = 0;
      for (int p = 0; p < 64; ++p) cn += pcnt[p * Kk + blk];
      if (cn > 0) cent[(size_t)blk * Hh + tid] = s / (float)cn;
    }
    if (blk == 0 && tid == 0) gflag[(it + 1) & 1] = 0;
    __threadfence();
    grid.sync();
    if (tid == 0) brk_l = atomicAdd(&gflag[it & 1], 0);
    __syncthreads();
    if (brk_l == 0) break;
  }
}

// ---------------------------------------------------------------------------
// h1 = relu(centers@g1_w + g1_b); h2 = relu(h1@g2_w + g2_b). One block.
__global__ __launch_bounds__(256) void gcn(
    const float* __restrict__ cent, const float* __restrict__ g1w,
    const float* __restrict__ g1b, const float* __restrict__ g2w,
    const float* __restrict__ g2b, float* __restrict__ h2out)
{
  __shared__ float a[Kk][Hh];
  __shared__ float b[Kk][Hh];
  int c = threadIdx.x;
  for (int i = c; i < Kk * Hh; i += 256) ((float*)a)[i] = cent[i];
  __syncthreads();
  float acc[Kk];
  #pragma unroll
  for (int k = 0; k < Kk; ++k) acc[k] = 0.f;
  for (int j = 0; j < Hh; ++j) {
    float wv = g1w[(size_t)j * Hh + c];
    #pragma unroll
    for (int k = 0; k < Kk; ++k) acc[k] += a[k][j] * wv;
  }
  #pragma unroll
  for (int k = 0; k < Kk; ++k) b[k][c] = fmaxf(acc[k] + g1b[c], 0.f);
  __syncthreads();
  #pragma unroll
  for (int k = 0; k < Kk; ++k) acc[k] = 0.f;
  for (int j = 0; j < Hh; ++j) {
    float wv = g2w[(size_t)j * Hh + c];
    #pragma unroll
    for (int k = 0; k < Kk; ++k) acc[k] += b[k][j] * wv;
  }
  #pragma unroll
  for (int k = 0; k < Kk; ++k) h2out[k * Hh + c] = fmaxf(acc[k] + g2b[c], 0.f);
}

// scores = softmax(relu(ht@centers^T)); clu = scores@h2; gated blend. 1 block/row.
__global__ __launch_bounds__(256) void finalk(
    const float* __restrict__ hfin, const float* __restrict__ cent,
    const float* __restrict__ h2, const float* __restrict__ w1w,
    const float* __restrict__ w1b, const float* __restrict__ w2w,
    const float* __restrict__ w2b, float* __restrict__ out)
{
  __shared__ alignas(16) float cs[Kk][Hh];
  __shared__ alignas(16) float hs[Kk][Hh];
  __shared__ float red[4];
  const int tid = threadIdx.x, lane = tid & 63, w = tid >> 6;
  const int n = blockIdx.x;
  for (int i = tid; i < Kk * Hh; i += 256) { ((float*)cs)[i] = cent[i]; ((float*)hs)[i] = h2[i]; }
  float ht = hfin[(size_t)n * Hh + tid];
  __syncthreads();

  auto bred = [&](float v) -> float {
    #pragma unroll
    for (int m = 1; m < 64; m <<= 1) v += __shfl_xor(v, m, 64);
    __syncthreads();
    if (lane == 0) red[w] = v;
    __syncthreads();
    return red[0] + red[1] + red[2] + red[3];
  };

  float ev[Kk];
  #pragma unroll
  for (int k = 0; k < Kk; ++k)
    ev[k] = fmaxf(bred(ht * cs[k][tid]), 0.f);

  float mx = ev[0];
  #pragma unroll
  for (int k = 1; k < Kk; ++k) mx = fmaxf(mx, ev[k]);
  float se = 0.f; float sc[Kk];
  #pragma unroll
  for (int k = 0; k < Kk; ++k) { sc[k] = expf(ev[k] - mx); se += sc[k]; }
  float inv = 1.f / se;
  float clu = 0.f;
  #pragma unroll
  for (int k = 0; k < Kk; ++k) clu += sc[k] * inv * hs[k][tid];

  float r1 = bred(clu * w1w[tid]);
  float r2 = bred(ht * w2w[tid]);
  float a1 = sigm(r1 + w1b[0]);
  float a2 = sigm(r2 + w2b[0]);
  float wn = a1 / (a1 + a2);
  out[(size_t)n * Hh + tid] = wn * clu + (1.f - wn) * ht;
}

// ---------------------------------------------------------------------------
// Host-side threefry2x32 (JAX), reproducing jax.random.permutation(key(42), 2048)[:12].
static void tf2x32(uint32_t k0, uint32_t k1, uint32_t c0, uint32_t c1,
                   uint32_t& o0, uint32_t& o1) {
  uint32_t ks2 = k0 ^ k1 ^ 0x1BD11BDAu;
  uint32_t x0 = c0 + k0, x1 = c1 + k1;
#define TFR(r) do { x0 += x1; x1 = (x1 << (r)) | (x1 >> (32 - (r))); x1 ^= x0; } while (0)
  TFR(13); TFR(15); TFR(26); TFR(6);
  x0 += k1;  x1 += ks2 + 1u;
  TFR(17); TFR(29); TFR(16); TFR(24);
  x0 += ks2; x1 += k0 + 2u;
  TFR(13); TFR(15); TFR(26); TFR(6);
  x0 += k0;  x1 += k1 + 3u;
  TFR(17); TFR(29); TFR(16); TFR(24);
  x0 += k1;  x1 += ks2 + 4u;
  TFR(13); TFR(15); TFR(26); TFR(6);
  x0 += ks2; x1 += k0 + 5u;
#undef TFR
  o0 = x0; o1 = x1;
}

static void compute_idx(int* out12) {
  uint32_t kh = 0u, kl = 42u;     // jax.random.key(42) -> (0, 42)
  std::vector<int> perm(Nn);
  for (int i = 0; i < Nn; ++i) perm[i] = i;
  std::vector<uint32_t> bits(Nn);
  std::vector<int> pos(Nn);
  for (int round = 0; round < 2; ++round) {     // 2 rounds for n=2048
    uint32_t nh, nl, sh, sl;
    tf2x32(kh, kl, 0u, 0u, nh, nl);             // split: counters (0,0),(0,1)
    tf2x32(kh, kl, 0u, 1u, sh, sl);
    kh = nh; kl = nl;
    // partitionable random_bits(32): bits[i] = o0 ^ o1 at counter (0, i)
    for (uint32_t i = 0; i < (uint32_t)Nn; ++i) {
      uint32_t o0, o1; tf2x32(sh, sl, 0u, i, o0, o1); bits[i] = o0 ^ o1;
    }
    for (int i = 0; i < Nn; ++i) pos[i] = i;
    std::stable_sort(pos.begin(), pos.end(),
                     [&](int a, int b) { return bits[a] < bits[b]; });
    std::vector<int> np(Nn);
    for (int i = 0; i < Nn; ++i) np[i] = perm[pos[i]];
    perm.swap(np);
  }
  for (int k = 0; k < Kk; ++k) out12[k] = perm[k];
}

// ---------------------------------------------------------------------------
extern "C" void kernel_launch(void* const* d_in, const int* in_sizes, int n_in,
                              void* d_out, int out_size, void* d_ws, size_t ws_size,
                              hipStream_t stream) {
  const float* x   = (const float*)d_in[0];
  const int*   len = (const int*)d_in[1];
  const float* Wih = (const float*)d_in[2];
  const float* Whh = (const float*)d_in[3];
  const float* bih = (const float*)d_in[4];
  const float* bhh = (const float*)d_in[5];
  const float* w1w = (const float*)d_in[6];
  const float* w1b = (const float*)d_in[7];
  const float* w2w = (const float*)d_in[8];
  const float* w2b = (const float*)d_in[9];
  const float* g1w = (const float*)d_in[10];
  const float* g1b = (const float*)d_in[11];
  const float* g2w = (const float*)d_in[12];
  const float* g2b = (const float*)d_in[13];
  float* out = (float*)d_out;

  float* wsf  = (float*)d_ws;
  float* hfin = wsf;                          // N*H
  float* cent = hfin + (size_t)Nn * Hh;       // K*H
  float* h2g  = cent + Kk * Hh;               // K*H
  float* part = h2g + Kk * Hh;                // 64*K*H
  int*   pcnt = (int*)(part + 64 * Kk * Hh);  // 64*K ints (pad to 1024)
  int*   gflag = pcnt + 768;                  // 2 ints
  float* pkw  = (float*)(pcnt + 1024);        // 393216 floats, 16B-aligned

  IdxArgs ia;
  compute_idx(ia.v);                          // host, deterministic, capture-safe

  pack_w<<<768, 64, 0, stream>>>(Wih, Whh, pkw);
  gru_q<<<256, 512, 0, stream>>>(x, len, pkw, bih, bhh, hfin);

  {
    void* ka[] = {(void*)&hfin, (void*)&cent, (void*)&part, (void*)&pcnt,
                  (void*)&gflag, (void*)&ia};
    hipLaunchCooperativeKernel((const void*)km_coop, dim3(64), dim3(256),
                               ka, 0, stream);
  }

  gcn<<<1, 256, 0, stream>>>(cent, g1w, g1b, g2w, g2b, h2g);
  finalk<<<Nn, 256, 0, stream>>>(hfin, cent, h2g, w1w, w1b, w2w, w2b, out);
}